// Round 2
// baseline (611.531 us; speedup 1.0000x reference)
//
#include <hip/hip_runtime.h>
#include <hip/hip_bf16.h>
#include <math.h>

// Problem constants
#define BATCH 4
#define SEQ 2048
#define FEAT 1024
#define HEADS 16
#define HDIM 64
#define FF 500
#define FFP 512                 // FF padded to multiple of 128
#define ROWS (BATCH * SEQ)      // 8192
#define QKVSTR 3072             // fused q|k|v row stride
#define AQ 128                  // attn q-rows per block

typedef unsigned short ushortT;
typedef __attribute__((ext_vector_type(8))) short short8;   // 8 bf16 (4 VGPRs)
typedef __attribute__((ext_vector_type(4))) float floatx4;  // MFMA acc
typedef __attribute__((ext_vector_type(2))) unsigned int uint2v;

#if defined(__has_builtin) && __has_builtin(__builtin_amdgcn_exp2f)
#define EXP2F(x) __builtin_amdgcn_exp2f(x)
#else
#define EXP2F(x) exp2f(x)
#endif

#if defined(__has_builtin)
#if __has_builtin(__builtin_amdgcn_permlane32_swap) && __has_builtin(__builtin_amdgcn_permlane16_swap)
#define HAVE_PLSWAP 1
#endif
#endif

__device__ __forceinline__ unsigned int f2bf(float f) {
    unsigned int u = __builtin_bit_cast(unsigned int, f);
    u += 0x7fffu + ((u >> 16) & 1u);           // RNE
    return (unsigned short)(u >> 16);
}
__device__ __forceinline__ float bf2f(short b) {
    unsigned int u = ((unsigned int)(unsigned short)b) << 16;
    return __builtin_bit_cast(float, u);
}

// pack two f32 -> one dword of 2x bf16 (RNE) without __builtin_bit_cast on
// the non-trivially-copyable __hip_bfloat162 type.
__device__ __forceinline__ unsigned int packbf2(float a, float b) {
    union { __hip_bfloat162 b2; unsigned int u; } c;
    c.b2 = __float22bfloat162_rn(make_float2(a, b));
    return c.u;
}

__device__ __forceinline__ unsigned int laneid() {
    return __builtin_amdgcn_mbcnt_hi(~0u, __builtin_amdgcn_mbcnt_lo(~0u, 0u));
}

// permlane32_swap semantics: ret.x = {a[0:32) ; b[0:32) moved to upper},
//                            ret.y = {a[32:64) moved to lower ; b[32:64)}
__device__ __forceinline__ uint2v pl32swap(unsigned int a, unsigned int b) {
#ifdef HAVE_PLSWAP
    return __builtin_amdgcn_permlane32_swap(a, b, false, false);
#else
    const unsigned int ln = laneid();
    unsigned int sa = (unsigned int)__shfl_xor((int)a, 32);
    unsigned int sb = (unsigned int)__shfl_xor((int)b, 32);
    uint2v r;
    r.x = (ln & 32) ? sb : a;
    r.y = (ln & 32) ? b : sa;
    return r;
#endif
}

// permlane16_swap semantics (per 32-half): ret.x = {a rows 0 ; b rows 0 -> 1},
//                                          ret.y = {a rows 1 -> 0 ; b rows 1}
__device__ __forceinline__ uint2v pl16swap(unsigned int a, unsigned int b) {
#ifdef HAVE_PLSWAP
    return __builtin_amdgcn_permlane16_swap(a, b, false, false);
#else
    const unsigned int ln = laneid();
    unsigned int sa = (unsigned int)__shfl_xor((int)a, 16);
    unsigned int sb = (unsigned int)__shfl_xor((int)b, 16);
    uint2v r;
    r.x = (ln & 16) ? sb : a;
    r.y = (ln & 16) ? b : sa;
    return r;
#endif
}

__device__ __forceinline__ void async16(void* lds, const void* g) {
    __builtin_amdgcn_global_load_lds(
        (const __attribute__((address_space(1))) unsigned int*)g,
        (__attribute__((address_space(3))) unsigned int*)lds, 16, 0, 0);
}

// ---------------------------------------------------------------------------
// Unified prep: 6 weight transpose+convert tiles + bias concat/pad.
// Blocks 0..1023: Wq/Wk/Wv/Wo (256 tiles each); 1024..1151: W1; 1152..1279: W2;
// 1280: biases.
// ---------------------------------------------------------------------------
__global__ void prep_kernel(const float* __restrict__ Wq, const float* __restrict__ Wk,
                            const float* __restrict__ Wv, const float* __restrict__ Wo,
                            const float* __restrict__ W1, const float* __restrict__ W2,
                            const float* __restrict__ bq, const float* __restrict__ bk,
                            const float* __restrict__ bv, const float* __restrict__ b1,
                            ushortT* __restrict__ Wqkvt, ushortT* __restrict__ Wot,
                            ushortT* __restrict__ W1t, ushortT* __restrict__ W2t,
                            float* __restrict__ bqkv, float* __restrict__ b1p)
{
    const int t = blockIdx.x;
    const int tid = threadIdx.x;
    if (t == 1280) {
        for (int i = tid; i < QKVSTR; i += 256)
            bqkv[i] = (i < 1024) ? bq[i] : ((i < 2048) ? bk[i - 1024] : bv[i - 2048]);
        for (int i = tid; i < FFP; i += 256)
            b1p[i] = (i < FF) ? b1[i] : 0.0f;
        return;
    }
    const float* W; ushortT* Wt; int K, N, Kp, bx, by;
    if (t < 1024) {
        const int wi = t >> 8, lt = t & 255;
        bx = lt & 15; by = lt >> 4; K = FEAT; N = FEAT; Kp = FEAT;
        W  = (wi == 0) ? Wq : (wi == 1) ? Wk : (wi == 2) ? Wv : Wo;
        Wt = (wi == 3) ? Wot : (Wqkvt + (size_t)wi * FEAT * FEAT);
    } else if (t < 1152) {
        const int lt = t - 1024; bx = lt & 7; by = lt >> 3;
        K = FEAT; N = FF; Kp = FEAT; W = W1; Wt = W1t;
    } else {
        const int lt = t - 1152; bx = lt & 15; by = lt >> 4;
        K = FF; N = FEAT; Kp = FFP; W = W2; Wt = W2t;
    }

    __shared__ float T[64][65];
    const int n0 = bx * 64, k0 = by * 64;
    const int r = tid >> 4;            // 0..15
    const int c = (tid & 15) * 4;      // 0..60
    #pragma unroll
    for (int i = 0; i < 4; i++) {
        const int kk = k0 + r + i * 16;
        #pragma unroll
        for (int e = 0; e < 4; e++) {
            const int nn = n0 + c + e;
            T[r + i * 16][c + e] = (kk < K && nn < N) ? W[(size_t)kk * N + nn] : 0.0f;
        }
    }
    __syncthreads();
    #pragma unroll
    for (int i = 0; i < 4; i++) {
        const int nn = r + i * 16;
        ushort4 o;
        o.x = f2bf(T[c + 0][nn]);
        o.y = f2bf(T[c + 1][nn]);
        o.z = f2bf(T[c + 2][nn]);
        o.w = f2bf(T[c + 3][nn]);
        *(ushort4*)(Wt + (size_t)(n0 + nn) * Kp + k0 + c) = o;
    }
}
// note: W1t has 512 rows allocated; rows 500..511 get zeros (T[][]=0 there),
// which is exactly the padding we want.

// ---------------------------------------------------------------------------
// Mask bit-pack: int32 0/1 [B,S,S] -> bitmask dwords [B,S,S/32].
// ---------------------------------------------------------------------------
__global__ void maskbits_kernel(const int* __restrict__ mask,
                                unsigned int* __restrict__ bits)
{
    const size_t g = (size_t)blockIdx.x * 256 + threadIdx.x;
    const int lane = threadIdx.x & 63;
    const unsigned long long bal = __ballot(mask[g] != 0);
    if (lane == 0)  bits[g >> 5] = (unsigned int)bal;
    if (lane == 32) bits[g >> 5] = (unsigned int)(bal >> 32);
}

// ---------------------------------------------------------------------------
// LayerNorm -> bf16. One block per row; wave-shuffle reduction, 1 barrier.
// ---------------------------------------------------------------------------
__global__ void ln_kernel(const float* __restrict__ x,
                          const float* __restrict__ alpha,
                          const float* __restrict__ bias,
                          ushortT* __restrict__ out)
{
    __shared__ float p1[4], p2[4];
    const int row = blockIdx.x;
    const int tid = threadIdx.x;
    const int wave = tid >> 6, lane = tid & 63;
    float4 v = ((const float4*)(x + (size_t)row * FEAT))[tid];

    float s1 = v.x + v.y + v.z + v.w;
    float s2 = v.x * v.x + v.y * v.y + v.z * v.z + v.w * v.w;
    #pragma unroll
    for (int off = 32; off > 0; off >>= 1) {
        s1 += __shfl_xor(s1, off);
        s2 += __shfl_xor(s2, off);
    }
    if (lane == 0) { p1[wave] = s1; p2[wave] = s2; }
    __syncthreads();
    const float t1 = p1[0] + p1[1] + p1[2] + p1[3];
    const float t2 = p2[0] + p2[1] + p2[2] + p2[3];
    const float mean = t1 * (1.0f / 1024.0f);
    const float var = fmaxf(t2 - 1024.0f * mean * mean, 0.0f) * (1.0f / 1023.0f);
    const float inv = 1.0f / (sqrtf(var) + 1e-6f);

    const float4 a = ((const float4*)alpha)[tid];
    const float4 b = ((const float4*)bias)[tid];
    ushort4 o;
    o.x = f2bf(a.x * (v.x - mean) * inv + b.x);
    o.y = f2bf(a.y * (v.y - mean) * inv + b.y);
    o.z = f2bf(a.z * (v.z - mean) * inv + b.z);
    o.w = f2bf(a.w * (v.w - mean) * inv + b.w);
    ((ushort4*)(out + (size_t)row * FEAT))[tid] = o;
}

// ---------------------------------------------------------------------------
// bf16 MFMA GEMM, BK=64 as two 32-K planes (keeps 64B LDS rows: conflict-free).
// 128xBN tile (BN=128: 2x2 waves, 4x4 frags; BN=64: 4x1 waves, 2x4 frags).
// ---------------------------------------------------------------------------
template<int ACT, int RES, int OUT_BF16, int BN>
__global__ __launch_bounds__(256)
void mfma_gemm(const ushortT* __restrict__ A, const ushortT* __restrict__ Bt,
               const float* __restrict__ bias, const float* __restrict__ R,
               void* __restrict__ Cout, int M, int N, int K)
{
    constexpr int MT = (BN == 128) ? 4 : 2;
    constexpr int MSPAN = (BN == 128) ? 64 : 32;
    __shared__ ushortT As[2][128 * 32];
    __shared__ ushortT Bs[2][BN * 32];

    const int tid  = threadIdx.x;
    const int wave = tid >> 6, lane = tid & 63;
    const int quad = lane >> 4, l16 = lane & 15;
    const int wm = (BN == 128) ? (wave >> 1) : wave;
    const int wn = (BN == 128) ? (wave & 1) : 0;
    const int row0 = blockIdx.y * 128, col0 = blockIdx.x * BN;

    const floatx4 z4 = {0.f, 0.f, 0.f, 0.f};
    floatx4 acc[MT][4];
    #pragma unroll
    for (int i = 0; i < MT; i++)
        #pragma unroll
        for (int j = 0; j < 4; j++) acc[i][j] = z4;

    for (int k0 = 0; k0 < K; k0 += 64) {
        __syncthreads();
        #pragma unroll
        for (int kh = 0; kh < 2; kh++) {
            #pragma unroll
            for (int i = 0; i < 2; i++) {
                const int rbase = 16 * (wave + 4 * i);
                const int r = rbase + (lane >> 2);
                const int co = (lane & 3) * 8;
                async16((char*)As[kh] + rbase * 64,
                        A + (size_t)(row0 + r) * K + k0 + kh * 32 + co);
            }
            if (BN == 128) {
                #pragma unroll
                for (int i = 0; i < 2; i++) {
                    const int rbase = 16 * (wave + 4 * i);
                    const int r = rbase + (lane >> 2);
                    const int co = (lane & 3) * 8;
                    async16((char*)Bs[kh] + rbase * 64,
                            Bt + (size_t)(col0 + r) * K + k0 + kh * 32 + co);
                }
            } else {
                const int rbase = 16 * wave;
                const int r = rbase + (lane >> 2);
                const int co = (lane & 3) * 8;
                async16((char*)Bs[kh] + rbase * 64,
                        Bt + (size_t)(col0 + r) * K + k0 + kh * 32 + co);
            }
        }
        __syncthreads();

        #pragma unroll
        for (int kh = 0; kh < 2; kh++) {
            short8 af[MT], bf[4];
            #pragma unroll
            for (int mt = 0; mt < MT; mt++)
                af[mt] = *(const short8*)&As[kh][(MSPAN * wm + 16 * mt + l16) * 32 + quad * 8];
            #pragma unroll
            for (int nt = 0; nt < 4; nt++)
                bf[nt] = *(const short8*)&Bs[kh][(64 * wn + 16 * nt + l16) * 32 + quad * 8];
            #pragma unroll
            for (int mt = 0; mt < MT; mt++)
                #pragma unroll
                for (int nt = 0; nt < 4; nt++)
                    acc[mt][nt] = __builtin_amdgcn_mfma_f32_16x16x32_bf16(
                        af[mt], bf[nt], acc[mt][nt], 0, 0, 0);
        }
    }

    #pragma unroll
    for (int mt = 0; mt < MT; mt++) {
        #pragma unroll
        for (int nt = 0; nt < 4; nt++) {
            const int col = col0 + 64 * wn + 16 * nt + l16;
            #pragma unroll
            for (int r = 0; r < 4; r++) {
                const int row = row0 + MSPAN * wm + 16 * mt + quad * 4 + r;
                float val = acc[mt][nt][r] + bias[col];
                if (ACT == 1) val = (val > 0.0f) ? val : (__expf(val) - 1.0f);
                if (RES) val += R[(size_t)row * N + col];
                if (OUT_BF16)
                    ((ushortT*)Cout)[(size_t)row * N + col] = f2bf(val);
                else
                    ((float*)Cout)[(size_t)row * N + col] = val;
            }
        }
    }
}

// ---------------------------------------------------------------------------
// V transpose: v bf16 (rows stride QKVSTR) -> vt bf16 [B][H][64 d][SEQ j]
// ---------------------------------------------------------------------------
__global__ void transpose_v_kernel(const ushortT* __restrict__ v, ushortT* __restrict__ vt)
{
    __shared__ ushortT T[64][80];
    const int bid = blockIdx.x;
    const int jt = bid & 31, h = (bid >> 5) & 15, b = bid >> 9;
    const int j0 = jt * 64;
    const int tid = threadIdx.x;

    const int j = tid >> 2;
    #pragma unroll
    for (int i = 0; i < 2; i++) {
        const int c = (tid & 3) * 2 + i;
        short8 val = *(const short8*)(v + (size_t)(b * SEQ + j0 + j) * QKVSTR + h * 64 + c * 8);
        *(short8*)&T[j][c * 8] = val;
    }
    __syncthreads();
    const int d = tid >> 2;
    #pragma unroll
    for (int i = 0; i < 2; i++) {
        const int cj = (tid & 3) * 2 + i;
        union { short8 v8; ushortT u[8]; } tmp;
        #pragma unroll
        for (int e = 0; e < 8; e++) tmp.u[e] = T[cj * 8 + e][d];
        *(short8*)(vt + ((size_t)((b * HEADS + h) * 64 + d)) * SEQ + j0 + cj * 8) = tmp.v8;
    }
}

// ---------------------------------------------------------------------------
// MFMA flash attention: 128 q-rows/block, 64-j tiles, no-max softmax, S^T
// form, dbuf K/V staging, one barrier/tile. P redistribution for the PV
// A-fragment is done fully in-register via permlane16/32_swap (no Ps LDS):
// lane (l16,q) holds P[m=l16][j=16nt+4q+r]; PV needs j=8q+i (pa0) and
// 32+8q+i (pa1). Per dword pair: PL32(D[even nt],D[odd nt]) then PL16
// lands exactly the fragment dwords. LDS = 32KB -> 4 blocks/CU resident.
// ---------------------------------------------------------------------------
__global__ __launch_bounds__(256, 4)
void mfma_attn(const ushortT* __restrict__ qkv, const ushortT* __restrict__ vt,
               const unsigned int* __restrict__ mbits, ushortT* __restrict__ attn_out)
{
    __shared__ ushortT Ks[2][64 * 64];    // [j][d] swizzled
    __shared__ ushortT Vts[2][64 * 64];   // [d][j] swizzled

    const int tid = threadIdx.x;
    const int wave = tid >> 6, lane = tid & 63;
    const int quad = lane >> 4, l16 = lane & 15;
    const int bid = blockIdx.x;
    const int qt = bid & 15, h = (bid >> 4) & 15, b = bid >> 8;
    const int q0 = qt * AQ;

    const ushortT* qptr = qkv;
    const ushortT* kptr = qkv + 1024;

    // Q fragments for both m-groups, pre-scaled by log2(e)/8.
    short8 qf[2][2];
    #pragma unroll
    for (int mg = 0; mg < 2; mg++) {
        const size_t qrow = (size_t)(b * SEQ + q0 + 32 * wave + mg * 16 + l16);
        short8 t0 = *(const short8*)(qptr + qrow * QKVSTR + h * 64 + quad * 8);
        short8 t1 = *(const short8*)(qptr + qrow * QKVSTR + h * 64 + 32 + quad * 8);
        const float cs = 0.125f * 1.4426950408889634f;
        #pragma unroll
        for (int i = 0; i < 8; i++) {
            qf[mg][0][i] = (short)f2bf(bf2f(t0[i]) * cs);
            qf[mg][1][i] = (short)f2bf(bf2f(t1[i]) * cs);
        }
    }

    short8 ones8;
    #pragma unroll
    for (int i = 0; i < 8; i++) ones8[i] = (short)0x3F80;  // bf16 1.0

    const floatx4 z4 = {0.f, 0.f, 0.f, 0.f};
    floatx4 o[2][4];
    #pragma unroll
    for (int mg = 0; mg < 2; mg++)
        #pragma unroll
        for (int dt = 0; dt < 4; dt++) o[mg][dt] = z4;
    floatx4 lacc[2] = {z4, z4};

    // staging pointers (advance per tile)
    const int rr = tid >> 2;
    const int c0 = (tid & 3) * 2;
    const ushortT* gk = kptr + (size_t)(b * SEQ + rr) * QKVSTR + h * 64;
    const ushortT* gv = vt + ((size_t)((b * HEADS + h) * 64 + rr)) * SEQ;
    short8 rk0, rk1, rv0, rv1;

#define ATTN_ISSUE() {                                                       \
    rk0 = *(const short8*)(gk + c0 * 8);                                     \
    rk1 = *(const short8*)(gk + c0 * 8 + 8);                                 \
    rv0 = *(const short8*)(gv + c0 * 8);                                     \
    rv1 = *(const short8*)(gv + c0 * 8 + 8);                                 \
    gk += (size_t)64 * QKVSTR; gv += 64; }

#define ATTN_WRITE(BI) {                                                     \
    *(short8*)&Ks[BI][rr * 64 + ((c0 ^ (rr & 7)) * 8)] = rk0;                \
    *(short8*)&Ks[BI][rr * 64 + (((c0 + 1) ^ (rr & 7)) * 8)] = rk1;          \
    *(short8*)&Vts[BI][rr * 64 + ((c0 ^ (rr & 7)) * 8)] = rv0;               \
    *(short8*)&Vts[BI][rr * 64 + (((c0 + 1) ^ (rr & 7)) * 8)] = rv1; }

    const unsigned int* mrowp[2];
    mrowp[0] = mbits + (size_t)(b * SEQ + q0 + 32 * wave + l16) * (SEQ / 32);
    mrowp[1] = mrowp[0] + 16 * (SEQ / 32);

    // Prologue: stage tile 0
    ATTN_ISSUE();
    ATTN_WRITE(0);

    #pragma unroll 2
    for (int jt = 0; jt < 32; jt++) {
        __syncthreads();
        const int cur = jt & 1;
        unsigned int w[2][2];
        #pragma unroll
        for (int mg = 0; mg < 2; mg++) {
            w[mg][0] = mrowp[mg][jt * 2];
            w[mg][1] = mrowp[mg][jt * 2 + 1];
        }
        if (jt < 31) ATTN_ISSUE();

        // S^T = K @ Q^T for both m-groups (K frags read once)
        floatx4 st[2][4];
        __builtin_amdgcn_s_setprio(1);
        #pragma unroll
        for (int nt = 0; nt < 4; nt++) {
            const int j = nt * 16 + l16;
            short8 ka0 = *(const short8*)&Ks[cur][j * 64 + ((quad ^ (j & 7)) * 8)];
            short8 ka1 = *(const short8*)&Ks[cur][j * 64 + (((4 + quad) ^ (j & 7)) * 8)];
            #pragma unroll
            for (int mg = 0; mg < 2; mg++) {
                floatx4 t = z4;
                t = __builtin_amdgcn_mfma_f32_16x16x32_bf16(ka0, qf[mg][0], t, 0, 0, 0);
                t = __builtin_amdgcn_mfma_f32_16x16x32_bf16(ka1, qf[mg][1], t, 0, 0, 0);
                st[mg][nt] = t;
            }
        }
        __builtin_amdgcn_s_setprio(0);

        // softmax: p = exp2(masked ? 0 : s); pack to bf16 pairs per nt.
        // Dw[mg][nt][dw] = bf16pair(p[2dw], p[2dw+1]) for j = 16nt+4quad+{..}
        unsigned int Dw[2][4][2];
        #pragma unroll
        for (int mg = 0; mg < 2; mg++) {
            #pragma unroll
            for (int nt = 0; nt < 4; nt++) {
                const unsigned int ww = (nt & 2) ? w[mg][1] : w[mg][0];
                const unsigned int wsh = ww >> ((nt & 1) * 16 + quad * 4);
                float p0 = EXP2F((wsh & 1u) ? st[mg][nt][0] : 0.0f);
                float p1 = EXP2F((wsh & 2u) ? st[mg][nt][1] : 0.0f);
                float p2 = EXP2F((wsh & 4u) ? st[mg][nt][2] : 0.0f);
                float p3 = EXP2F((wsh & 8u) ? st[mg][nt][3] : 0.0f);
                Dw[mg][nt][0] = packbf2(p0, p1);
                Dw[mg][nt][1] = packbf2(p2, p3);
            }
        }

        // In-register redistribution to PV A-fragments.
        // After PL32(D[e][dw], D[o][dw]):  x: Q0=s0.De Q1=s1.De Q2=s0.Do Q3=s1.Do
        //                                  y: Q0=s2.De Q1=s3.De Q2=s2.Do Q3=s3.Do
        // After PL16(x, y):                x: Q0=s0.De Q1=s2.De Q2=s0.Do Q3=s2.Do
        //                                  y: Q0=s1.De Q1=s3.De Q2=s1.Do Q3=s3.Do
        // which are exactly pa dwords {dw} and {2+dw}.
        short8 pa[2][2];
        #pragma unroll
        for (int mg = 0; mg < 2; mg++) {
            union { unsigned int u[4]; short8 v; } o0, o1;
            #pragma unroll
            for (int dw = 0; dw < 2; dw++) {
                uint2v s1 = pl32swap(Dw[mg][0][dw], Dw[mg][1][dw]);
                uint2v f1 = pl16swap(s1.x, s1.y);
                o0.u[dw] = f1.x; o0.u[2 + dw] = f1.y;
                uint2v s2 = pl32swap(Dw[mg][2][dw], Dw[mg][3][dw]);
                uint2v f2 = pl16swap(s2.x, s2.y);
                o1.u[dw] = f2.x; o1.u[2 + dw] = f2.y;
            }
            pa[mg][0] = o0.v;
            pa[mg][1] = o1.v;
            lacc[mg] = __builtin_amdgcn_mfma_f32_16x16x32_bf16(pa[mg][0], ones8, lacc[mg], 0, 0, 0);
            lacc[mg] = __builtin_amdgcn_mfma_f32_16x16x32_bf16(pa[mg][1], ones8, lacc[mg], 0, 0, 0);
        }

        // O += P @ V
        __builtin_amdgcn_s_setprio(1);
        #pragma unroll
        for (int dt = 0; dt < 4; dt++) {
            const int d = dt * 16 + l16;
            short8 vb0 = *(const short8*)&Vts[cur][d * 64 + ((quad ^ (d & 7)) * 8)];
            short8 vb1 = *(const short8*)&Vts[cur][d * 64 + (((4 + quad) ^ (d & 7)) * 8)];
            #pragma unroll
            for (int mg = 0; mg < 2; mg++) {
                o[mg][dt] = __builtin_amdgcn_mfma_f32_16x16x32_bf16(pa[mg][0], vb0, o[mg][dt], 0, 0, 0);
                o[mg][dt] = __builtin_amdgcn_mfma_f32_16x16x32_bf16(pa[mg][1], vb1, o[mg][dt], 0, 0, 0);
            }
        }
        __builtin_amdgcn_s_setprio(0);

        if (jt < 31) ATTN_WRITE(cur ^ 1);
    }

    // Normalize + store bf16.
    #pragma unroll
    for (int mg = 0; mg < 2; mg++) {
        #pragma unroll
        for (int r = 0; r < 4; r++) {
            const float inv_l = 1.0f / lacc[mg][r];
            const size_t row = (size_t)(b * SEQ + q0 + 32 * wave + mg * 16 + quad * 4 + r);
            #pragma unroll
            for (int dt = 0; dt < 4; dt++) {
                attn_out[row * FEAT + h * 64 + dt * 16 + l16] = f2bf(o[mg][dt][r] * inv_l);
            }
        }
    }
#undef ATTN_ISSUE
#undef ATTN_WRITE
}

// ---------------------------------------------------------------------------
// Launch
// ---------------------------------------------------------------------------
extern "C" void kernel_launch(void* const* d_in, const int* in_sizes, int n_in,
                              void* d_out, int out_size, void* d_ws, size_t ws_size,
                              hipStream_t stream)
{
    const float* x      = (const float*)d_in[0];
    const int*   mask   = (const int*)d_in[1];
    const float* alpha1 = (const float*)d_in[2];
    const float* bias1  = (const float*)d_in[3];
    const float* alpha2 = (const float*)d_in[4];
    const float* bias2  = (const float*)d_in[5];
    const float* Wq     = (const float*)d_in[6];
    const float* bq     = (const float*)d_in[7];
    const float* Wk     = (const float*)d_in[8];
    const float* bk     = (const float*)d_in[9];
    const float* Wv     = (const float*)d_in[10];
    const float* bv     = (const float*)d_in[11];
    const float* Wo     = (const float*)d_in[12];
    const float* bo     = (const float*)d_in[13];
    const float* W1     = (const float*)d_in[14];
    const float* b1     = (const float*)d_in[15];
    const float* W2     = (const float*)d_in[16];
    const float* b2     = (const float*)d_in[17];
    float* out = (float*)d_out;

    char* ws = (char*)d_ws;
    const size_t MB = 1024 * 1024;
    ushortT* x2b    = (ushortT*)(ws);              // LN1 out; attn out later
    ushortT* attn_o = (ushortT*)(ws);
    ushortT* qkv    = (ushortT*)(ws + 16 * MB);    // fused q|k|v
    ushortT* x2b2   = (ushortT*)(ws + 16 * MB);    // LN2 out (after attn)
    ushortT* hbuf   = (ushortT*)(ws + 32 * MB);    // FF hidden
    ushortT* vtb    = (ushortT*)(ws + 64 * MB);
    ushortT* Wqkvt  = (ushortT*)(ws + 80 * MB);    // 6 MB  [3072][1024]
    ushortT* Wot    = (ushortT*)(ws + 86 * MB);    // 2 MB
    ushortT* W1t    = (ushortT*)(ws + 88 * MB);    // 1 MB  [512][1024]
    ushortT* W2t    = (ushortT*)(ws + 89 * MB);    // 1 MB  [1024][512]
    float*   b1p    = (float*)  (ws + 90 * MB);
    float*   bqkv   = (float*)  (ws + 90 * MB + 16384);
    unsigned int* mbits = (unsigned int*)(ws + 91 * MB); // 2 MB

    const dim3 blk(256);

    // Prep (1 launch) + mask pack
    prep_kernel<<<1281, blk, 0, stream>>>(Wq, Wk, Wv, Wo, W1, W2, bq, bk, bv, b1,
                                          Wqkvt, Wot, W1t, W2t, bqkv, b1p);
    maskbits_kernel<<<(BATCH * SEQ * SEQ) / 256, blk, 0, stream>>>(mask, mbits);

    // 1. LN1 -> bf16
    ln_kernel<<<ROWS, blk, 0, stream>>>(x, alpha1, bias1, x2b);

    // 2. Fused QKV projection
    mfma_gemm<0, 0, 1, 128><<<dim3(24, 64), blk, 0, stream>>>(
        x2b, Wqkvt, bqkv, nullptr, qkv, ROWS, QKVSTR, FEAT);

    // 3. V transpose + flash attention
    transpose_v_kernel<<<BATCH * HEADS * (SEQ / 64), blk, 0, stream>>>(qkv + 2048, vtb);
    mfma_attn<<<BATCH * HEADS * (SEQ / AQ), blk, 0, stream>>>(qkv, vtb, mbits, attn_o);

    // 4. out = x + attn @ Wo + bo
    mfma_gemm<0, 1, 0, 128><<<dim3(8, 64), blk, 0, stream>>>(
        attn_o, Wot, bo, x, out, ROWS, FEAT, FEAT);

    // 5. LN2 -> bf16
    ln_kernel<<<ROWS, blk, 0, stream>>>(out, alpha2, bias2, x2b2);

    // 6. h = ELU(x2b2 @ W1 + b1)
    mfma_gemm<1, 0, 1, 64><<<dim3(FFP / 64, 64), blk, 0, stream>>>(
        x2b2, W1t, b1p, nullptr, hbuf, ROWS, FFP, FEAT);

    // 7. out += h @ W2 + b2
    mfma_gemm<0, 1, 0, 128><<<dim3(8, 64), blk, 0, stream>>>(
        hbuf, W2t, b2, out, out, ROWS, FEAT, FFP);
}

// Round 3
// 485.753 us; speedup vs baseline: 1.2589x; 1.2589x over previous
//
#include <hip/hip_runtime.h>
#include <hip/hip_bf16.h>
#include <math.h>

// Problem constants
#define BATCH 4
#define SEQ 2048
#define FEAT 1024
#define HEADS 16
#define HDIM 64
#define FF 500
#define FFP 512                 // FF padded to multiple of 128
#define ROWS (BATCH * SEQ)      // 8192
#define QKVSTR 3072             // fused q|k|v row stride
#define AQ 128                  // attn q-rows per block

typedef unsigned short ushortT;
typedef __attribute__((ext_vector_type(8))) short short8;   // 8 bf16 (4 VGPRs)
typedef __attribute__((ext_vector_type(4))) float floatx4;  // MFMA acc
typedef __attribute__((ext_vector_type(2))) unsigned int uint2v;
typedef __attribute__((ext_vector_type(4))) unsigned int uint4v;

#if defined(__has_builtin) && __has_builtin(__builtin_amdgcn_exp2f)
#define EXP2F(x) __builtin_amdgcn_exp2f(x)
#else
#define EXP2F(x) exp2f(x)
#endif

#if defined(__has_builtin)
#if __has_builtin(__builtin_amdgcn_permlane32_swap) && __has_builtin(__builtin_amdgcn_permlane16_swap)
#define HAVE_PLSWAP 1
#endif
#endif

__device__ __forceinline__ unsigned int f2bf(float f) {
    unsigned int u = __builtin_bit_cast(unsigned int, f);
    u += 0x7fffu + ((u >> 16) & 1u);           // RNE
    return (u >> 16) & 0xffffu;
}
__device__ __forceinline__ float bf2f(short b) {
    unsigned int u = ((unsigned int)(unsigned short)b) << 16;
    return __builtin_bit_cast(float, u);
}
// pack two f32 -> one dword of 2x bf16 (RNE), pure bit ops (no union: SROA-safe)
__device__ __forceinline__ unsigned int packbf2(float lo, float hi) {
    return (f2bf(hi) << 16) | f2bf(lo);
}

__device__ __forceinline__ unsigned int laneid() {
    return __builtin_amdgcn_mbcnt_hi(~0u, __builtin_amdgcn_mbcnt_lo(~0u, 0u));
}

// permlane32_swap semantics: ret.x = {a[0:32) ; b[0:32) moved to upper},
//                            ret.y = {a[32:64) moved to lower ; b[32:64)}
__device__ __forceinline__ uint2v pl32swap(unsigned int a, unsigned int b) {
#ifdef HAVE_PLSWAP
    return __builtin_amdgcn_permlane32_swap(a, b, false, false);
#else
    const unsigned int ln = laneid();
    unsigned int sa = (unsigned int)__shfl_xor((int)a, 32);
    unsigned int sb = (unsigned int)__shfl_xor((int)b, 32);
    uint2v r;
    r.x = (ln & 32) ? sb : a;
    r.y = (ln & 32) ? b : sa;
    return r;
#endif
}

// permlane16_swap semantics (per 32-half): ret.x = {a rows 0 ; b rows 0 -> 1},
//                                          ret.y = {a rows 1 -> 0 ; b rows 1}
__device__ __forceinline__ uint2v pl16swap(unsigned int a, unsigned int b) {
#ifdef HAVE_PLSWAP
    return __builtin_amdgcn_permlane16_swap(a, b, false, false);
#else
    const unsigned int ln = laneid();
    unsigned int sa = (unsigned int)__shfl_xor((int)a, 16);
    unsigned int sb = (unsigned int)__shfl_xor((int)b, 16);
    uint2v r;
    r.x = (ln & 16) ? sb : a;
    r.y = (ln & 16) ? b : sa;
    return r;
#endif
}

__device__ __forceinline__ void async16(void* lds, const void* g) {
    __builtin_amdgcn_global_load_lds(
        (const __attribute__((address_space(1))) unsigned int*)g,
        (__attribute__((address_space(3))) unsigned int*)lds, 16, 0, 0);
}

// ---------------------------------------------------------------------------
// Unified prep: 6 weight transpose+convert tiles + bias concat/pad.
// Blocks 0..1023: Wq/Wk/Wv/Wo (256 tiles each); 1024..1151: W1; 1152..1279: W2;
// 1280: biases.
// ---------------------------------------------------------------------------
__global__ void prep_kernel(const float* __restrict__ Wq, const float* __restrict__ Wk,
                            const float* __restrict__ Wv, const float* __restrict__ Wo,
                            const float* __restrict__ W1, const float* __restrict__ W2,
                            const float* __restrict__ bq, const float* __restrict__ bk,
                            const float* __restrict__ bv, const float* __restrict__ b1,
                            ushortT* __restrict__ Wqkvt, ushortT* __restrict__ Wot,
                            ushortT* __restrict__ W1t, ushortT* __restrict__ W2t,
                            float* __restrict__ bqkv, float* __restrict__ b1p)
{
    const int t = blockIdx.x;
    const int tid = threadIdx.x;
    if (t == 1280) {
        for (int i = tid; i < QKVSTR; i += 256)
            bqkv[i] = (i < 1024) ? bq[i] : ((i < 2048) ? bk[i - 1024] : bv[i - 2048]);
        for (int i = tid; i < FFP; i += 256)
            b1p[i] = (i < FF) ? b1[i] : 0.0f;
        return;
    }
    const float* W; ushortT* Wt; int K, N, Kp, bx, by;
    if (t < 1024) {
        const int wi = t >> 8, lt = t & 255;
        bx = lt & 15; by = lt >> 4; K = FEAT; N = FEAT; Kp = FEAT;
        W  = (wi == 0) ? Wq : (wi == 1) ? Wk : (wi == 2) ? Wv : Wo;
        Wt = (wi == 3) ? Wot : (Wqkvt + (size_t)wi * FEAT * FEAT);
    } else if (t < 1152) {
        const int lt = t - 1024; bx = lt & 7; by = lt >> 3;
        K = FEAT; N = FF; Kp = FEAT; W = W1; Wt = W1t;
    } else {
        const int lt = t - 1152; bx = lt & 15; by = lt >> 4;
        K = FF; N = FEAT; Kp = FFP; W = W2; Wt = W2t;
    }

    __shared__ float T[64][65];
    const int n0 = bx * 64, k0 = by * 64;
    const int r = tid >> 4;            // 0..15
    const int c = (tid & 15) * 4;      // 0..60
    #pragma unroll
    for (int i = 0; i < 4; i++) {
        const int kk = k0 + r + i * 16;
        #pragma unroll
        for (int e = 0; e < 4; e++) {
            const int nn = n0 + c + e;
            T[r + i * 16][c + e] = (kk < K && nn < N) ? W[(size_t)kk * N + nn] : 0.0f;
        }
    }
    __syncthreads();
    #pragma unroll
    for (int i = 0; i < 4; i++) {
        const int nn = r + i * 16;
        ushort4 o;
        o.x = (ushortT)f2bf(T[c + 0][nn]);
        o.y = (ushortT)f2bf(T[c + 1][nn]);
        o.z = (ushortT)f2bf(T[c + 2][nn]);
        o.w = (ushortT)f2bf(T[c + 3][nn]);
        *(ushort4*)(Wt + (size_t)(n0 + nn) * Kp + k0 + c) = o;
    }
}
// note: W1t has 512 rows allocated; rows 500..511 get zeros (T[][]=0 there),
// which is exactly the padding we want.

// ---------------------------------------------------------------------------
// Mask bit-pack: int32 0/1 [B,S,S] -> bitmask dwords [B,S,S/32].
// ---------------------------------------------------------------------------
__global__ void maskbits_kernel(const int* __restrict__ mask,
                                unsigned int* __restrict__ bits)
{
    const size_t g = (size_t)blockIdx.x * 256 + threadIdx.x;
    const int lane = threadIdx.x & 63;
    const unsigned long long bal = __ballot(mask[g] != 0);
    if (lane == 0)  bits[g >> 5] = (unsigned int)bal;
    if (lane == 32) bits[g >> 5] = (unsigned int)(bal >> 32);
}

// ---------------------------------------------------------------------------
// LayerNorm -> bf16. One block per row; wave-shuffle reduction, 1 barrier.
// ---------------------------------------------------------------------------
__global__ void ln_kernel(const float* __restrict__ x,
                          const float* __restrict__ alpha,
                          const float* __restrict__ bias,
                          ushortT* __restrict__ out)
{
    __shared__ float p1[4], p2[4];
    const int row = blockIdx.x;
    const int tid = threadIdx.x;
    const int wave = tid >> 6, lane = tid & 63;
    float4 v = ((const float4*)(x + (size_t)row * FEAT))[tid];

    float s1 = v.x + v.y + v.z + v.w;
    float s2 = v.x * v.x + v.y * v.y + v.z * v.z + v.w * v.w;
    #pragma unroll
    for (int off = 32; off > 0; off >>= 1) {
        s1 += __shfl_xor(s1, off);
        s2 += __shfl_xor(s2, off);
    }
    if (lane == 0) { p1[wave] = s1; p2[wave] = s2; }
    __syncthreads();
    const float t1 = p1[0] + p1[1] + p1[2] + p1[3];
    const float t2 = p2[0] + p2[1] + p2[2] + p2[3];
    const float mean = t1 * (1.0f / 1024.0f);
    const float var = fmaxf(t2 - 1024.0f * mean * mean, 0.0f) * (1.0f / 1023.0f);
    const float inv = 1.0f / (sqrtf(var) + 1e-6f);

    const float4 a = ((const float4*)alpha)[tid];
    const float4 b = ((const float4*)bias)[tid];
    ushort4 o;
    o.x = (ushortT)f2bf(a.x * (v.x - mean) * inv + b.x);
    o.y = (ushortT)f2bf(a.y * (v.y - mean) * inv + b.y);
    o.z = (ushortT)f2bf(a.z * (v.z - mean) * inv + b.z);
    o.w = (ushortT)f2bf(a.w * (v.w - mean) * inv + b.w);
    ((ushort4*)(out + (size_t)row * FEAT))[tid] = o;
}

// ---------------------------------------------------------------------------
// bf16 MFMA GEMM, BK=64 as two 32-K planes (keeps 64B LDS rows: conflict-free).
// 128xBN tile (BN=128: 2x2 waves, 4x4 frags; BN=64: 4x1 waves, 2x4 frags).
// ---------------------------------------------------------------------------
template<int ACT, int RES, int OUT_BF16, int BN>
__global__ __launch_bounds__(256)
void mfma_gemm(const ushortT* __restrict__ A, const ushortT* __restrict__ Bt,
               const float* __restrict__ bias, const float* __restrict__ R,
               void* __restrict__ Cout, int M, int N, int K)
{
    constexpr int MT = (BN == 128) ? 4 : 2;
    constexpr int MSPAN = (BN == 128) ? 64 : 32;
    __shared__ ushortT As[2][128 * 32];
    __shared__ ushortT Bs[2][BN * 32];

    const int tid  = threadIdx.x;
    const int wave = tid >> 6, lane = tid & 63;
    const int quad = lane >> 4, l16 = lane & 15;
    const int wm = (BN == 128) ? (wave >> 1) : wave;
    const int wn = (BN == 128) ? (wave & 1) : 0;
    const int row0 = blockIdx.y * 128, col0 = blockIdx.x * BN;

    const floatx4 z4 = {0.f, 0.f, 0.f, 0.f};
    floatx4 acc[MT][4];
    #pragma unroll
    for (int i = 0; i < MT; i++)
        #pragma unroll
        for (int j = 0; j < 4; j++) acc[i][j] = z4;

    for (int k0 = 0; k0 < K; k0 += 64) {
        __syncthreads();
        #pragma unroll
        for (int kh = 0; kh < 2; kh++) {
            #pragma unroll
            for (int i = 0; i < 2; i++) {
                const int rbase = 16 * (wave + 4 * i);
                const int r = rbase + (lane >> 2);
                const int co = (lane & 3) * 8;
                async16((char*)As[kh] + rbase * 64,
                        A + (size_t)(row0 + r) * K + k0 + kh * 32 + co);
            }
            if (BN == 128) {
                #pragma unroll
                for (int i = 0; i < 2; i++) {
                    const int rbase = 16 * (wave + 4 * i);
                    const int r = rbase + (lane >> 2);
                    const int co = (lane & 3) * 8;
                    async16((char*)Bs[kh] + rbase * 64,
                            Bt + (size_t)(col0 + r) * K + k0 + kh * 32 + co);
                }
            } else {
                const int rbase = 16 * wave;
                const int r = rbase + (lane >> 2);
                const int co = (lane & 3) * 8;
                async16((char*)Bs[kh] + rbase * 64,
                        Bt + (size_t)(col0 + r) * K + k0 + kh * 32 + co);
            }
        }
        __syncthreads();

        #pragma unroll
        for (int kh = 0; kh < 2; kh++) {
            short8 af[MT], bf[4];
            #pragma unroll
            for (int mt = 0; mt < MT; mt++)
                af[mt] = *(const short8*)&As[kh][(MSPAN * wm + 16 * mt + l16) * 32 + quad * 8];
            #pragma unroll
            for (int nt = 0; nt < 4; nt++)
                bf[nt] = *(const short8*)&Bs[kh][(64 * wn + 16 * nt + l16) * 32 + quad * 8];
            #pragma unroll
            for (int mt = 0; mt < MT; mt++)
                #pragma unroll
                for (int nt = 0; nt < 4; nt++)
                    acc[mt][nt] = __builtin_amdgcn_mfma_f32_16x16x32_bf16(
                        af[mt], bf[nt], acc[mt][nt], 0, 0, 0);
        }
    }

    #pragma unroll
    for (int mt = 0; mt < MT; mt++) {
        #pragma unroll
        for (int nt = 0; nt < 4; nt++) {
            const int col = col0 + 64 * wn + 16 * nt + l16;
            #pragma unroll
            for (int r = 0; r < 4; r++) {
                const int row = row0 + MSPAN * wm + 16 * mt + quad * 4 + r;
                float val = acc[mt][nt][r] + bias[col];
                if (ACT == 1) val = (val > 0.0f) ? val : (__expf(val) - 1.0f);
                if (RES) val += R[(size_t)row * N + col];
                if (OUT_BF16)
                    ((ushortT*)Cout)[(size_t)row * N + col] = (ushortT)f2bf(val);
                else
                    ((float*)Cout)[(size_t)row * N + col] = val;
            }
        }
    }
}

// ---------------------------------------------------------------------------
// V transpose: v bf16 (rows stride QKVSTR) -> vt bf16 [B][H][64 d][SEQ j]
// ---------------------------------------------------------------------------
__global__ void transpose_v_kernel(const ushortT* __restrict__ v, ushortT* __restrict__ vt)
{
    __shared__ ushortT T[64][80];
    const int bid = blockIdx.x;
    const int jt = bid & 31, h = (bid >> 5) & 15, b = bid >> 9;
    const int j0 = jt * 64;
    const int tid = threadIdx.x;

    const int j = tid >> 2;
    #pragma unroll
    for (int i = 0; i < 2; i++) {
        const int c = (tid & 3) * 2 + i;
        short8 val = *(const short8*)(v + (size_t)(b * SEQ + j0 + j) * QKVSTR + h * 64 + c * 8);
        *(short8*)&T[j][c * 8] = val;
    }
    __syncthreads();
    const int d = tid >> 2;
    #pragma unroll
    for (int i = 0; i < 2; i++) {
        const int cj = (tid & 3) * 2 + i;
        short8 tmp;
        #pragma unroll
        for (int e = 0; e < 8; e++) tmp[e] = (short)T[cj * 8 + e][d];
        *(short8*)(vt + ((size_t)((b * HEADS + h) * 64 + d)) * SEQ + j0 + cj * 8) = tmp;
    }
}

// ---------------------------------------------------------------------------
// MFMA flash attention: 128 q-rows/block, 64-j tiles, no-max softmax, S^T
// form, dbuf K/V staging, one barrier/tile. P redistribution for the PV
// A-fragment is done fully in-register via permlane16/32_swap (no Ps LDS):
// lane (l16,q) holds P[m=l16][j=16nt+4q+r]; PV needs j=8q+i (pa0) and
// 32+8q+i (pa1). Per dword pair: PL32(D[even nt],D[odd nt]) then PL16
// lands exactly the fragment dwords. All temporaries are scalars/ext-vectors
// (NO unions -- round-2 unions went to scratch: 690 MB spill traffic).
// LDS = 32KB -> 4 blocks/CU resident (grid-capped).
// ---------------------------------------------------------------------------
__global__ __launch_bounds__(256)
void mfma_attn(const ushortT* __restrict__ qkv, const ushortT* __restrict__ vt,
               const unsigned int* __restrict__ mbits, ushortT* __restrict__ attn_out)
{
    __shared__ ushortT Ks[2][64 * 64];    // [j][d] swizzled
    __shared__ ushortT Vts[2][64 * 64];   // [d][j] swizzled

    const int tid = threadIdx.x;
    const int wave = tid >> 6, lane = tid & 63;
    const int quad = lane >> 4, l16 = lane & 15;
    const int bid = blockIdx.x;
    const int qt = bid & 15, h = (bid >> 4) & 15, b = bid >> 8;
    const int q0 = qt * AQ;

    const ushortT* qptr = qkv;
    const ushortT* kptr = qkv + 1024;

    // Q fragments for both m-groups, pre-scaled by log2(e)/8.
    short8 qf[2][2];
    #pragma unroll
    for (int mg = 0; mg < 2; mg++) {
        const size_t qrow = (size_t)(b * SEQ + q0 + 32 * wave + mg * 16 + l16);
        short8 t0 = *(const short8*)(qptr + qrow * QKVSTR + h * 64 + quad * 8);
        short8 t1 = *(const short8*)(qptr + qrow * QKVSTR + h * 64 + 32 + quad * 8);
        const float cs = 0.125f * 1.4426950408889634f;
        #pragma unroll
        for (int i = 0; i < 8; i++) {
            qf[mg][0][i] = (short)f2bf(bf2f(t0[i]) * cs);
            qf[mg][1][i] = (short)f2bf(bf2f(t1[i]) * cs);
        }
    }

    short8 ones8;
    #pragma unroll
    for (int i = 0; i < 8; i++) ones8[i] = (short)0x3F80;  // bf16 1.0

    const floatx4 z4 = {0.f, 0.f, 0.f, 0.f};
    floatx4 o[2][4];
    #pragma unroll
    for (int mg = 0; mg < 2; mg++)
        #pragma unroll
        for (int dt = 0; dt < 4; dt++) o[mg][dt] = z4;
    floatx4 lacc[2] = {z4, z4};

    // staging pointers (advance per tile)
    const int rr = tid >> 2;
    const int c0 = (tid & 3) * 2;
    const ushortT* gk = kptr + (size_t)(b * SEQ + rr) * QKVSTR + h * 64;
    const ushortT* gv = vt + ((size_t)((b * HEADS + h) * 64 + rr)) * SEQ;
    short8 rk0, rk1, rv0, rv1;

#define ATTN_ISSUE() {                                                       \
    rk0 = *(const short8*)(gk + c0 * 8);                                     \
    rk1 = *(const short8*)(gk + c0 * 8 + 8);                                 \
    rv0 = *(const short8*)(gv + c0 * 8);                                     \
    rv1 = *(const short8*)(gv + c0 * 8 + 8);                                 \
    gk += (size_t)64 * QKVSTR; gv += 64; }

#define ATTN_WRITE(BI) {                                                     \
    *(short8*)&Ks[BI][rr * 64 + ((c0 ^ (rr & 7)) * 8)] = rk0;                \
    *(short8*)&Ks[BI][rr * 64 + (((c0 + 1) ^ (rr & 7)) * 8)] = rk1;          \
    *(short8*)&Vts[BI][rr * 64 + ((c0 ^ (rr & 7)) * 8)] = rv0;               \
    *(short8*)&Vts[BI][rr * 64 + (((c0 + 1) ^ (rr & 7)) * 8)] = rv1; }

    const unsigned int* mrowp[2];
    mrowp[0] = mbits + (size_t)(b * SEQ + q0 + 32 * wave + l16) * (SEQ / 32);
    mrowp[1] = mrowp[0] + 16 * (SEQ / 32);

    // Prologue: stage tile 0
    ATTN_ISSUE();
    ATTN_WRITE(0);

    #pragma unroll 2
    for (int jt = 0; jt < 32; jt++) {
        __syncthreads();
        const int cur = jt & 1;
        unsigned int w[2][2];
        #pragma unroll
        for (int mg = 0; mg < 2; mg++) {
            w[mg][0] = mrowp[mg][jt * 2];
            w[mg][1] = mrowp[mg][jt * 2 + 1];
        }
        if (jt < 31) ATTN_ISSUE();

        // S^T = K @ Q^T for both m-groups (K frags read once)
        floatx4 st[2][4];
        __builtin_amdgcn_s_setprio(1);
        #pragma unroll
        for (int nt = 0; nt < 4; nt++) {
            const int j = nt * 16 + l16;
            short8 ka0 = *(const short8*)&Ks[cur][j * 64 + ((quad ^ (j & 7)) * 8)];
            short8 ka1 = *(const short8*)&Ks[cur][j * 64 + (((4 + quad) ^ (j & 7)) * 8)];
            #pragma unroll
            for (int mg = 0; mg < 2; mg++) {
                floatx4 t = z4;
                t = __builtin_amdgcn_mfma_f32_16x16x32_bf16(ka0, qf[mg][0], t, 0, 0, 0);
                t = __builtin_amdgcn_mfma_f32_16x16x32_bf16(ka1, qf[mg][1], t, 0, 0, 0);
                st[mg][nt] = t;
            }
        }
        __builtin_amdgcn_s_setprio(0);

        // softmax: p = exp2(masked ? 0 : s); pack to bf16-pair dwords per nt.
        // Dw[mg][nt][dw] = bf16pair(p[2dw], p[2dw+1]) for j = 16nt+4quad+{..}
        unsigned int Dw[2][4][2];
        #pragma unroll
        for (int mg = 0; mg < 2; mg++) {
            #pragma unroll
            for (int nt = 0; nt < 4; nt++) {
                const unsigned int ww = (nt & 2) ? w[mg][1] : w[mg][0];
                const unsigned int wsh = ww >> ((nt & 1) * 16 + quad * 4);
                float p0 = EXP2F((wsh & 1u) ? st[mg][nt][0] : 0.0f);
                float p1 = EXP2F((wsh & 2u) ? st[mg][nt][1] : 0.0f);
                float p2 = EXP2F((wsh & 4u) ? st[mg][nt][2] : 0.0f);
                float p3 = EXP2F((wsh & 8u) ? st[mg][nt][3] : 0.0f);
                Dw[mg][nt][0] = packbf2(p0, p1);
                Dw[mg][nt][1] = packbf2(p2, p3);
            }
        }

        // In-register redistribution to PV A-fragments.
        // After PL32(D[e][dw], D[o][dw]):  x: Q0=s0.De Q1=s1.De Q2=s0.Do Q3=s1.Do
        //                                  y: Q0=s2.De Q1=s3.De Q2=s2.Do Q3=s3.Do
        // After PL16(x, y):                x: Q0=s0.De Q1=s2.De Q2=s0.Do Q3=s2.Do
        //                                  y: Q0=s1.De Q1=s3.De Q2=s1.Do Q3=s3.Do
        // which are exactly pa dwords {dw} and {2+dw}.
        short8 pa[2][2];
        #pragma unroll
        for (int mg = 0; mg < 2; mg++) {
            uint4v a0, a1;
            {   // dw = 0
                uint2v s1 = pl32swap(Dw[mg][0][0], Dw[mg][1][0]);
                uint2v f1 = pl16swap(s1.x, s1.y);
                a0.x = f1.x; a0.z = f1.y;
                uint2v s2 = pl32swap(Dw[mg][2][0], Dw[mg][3][0]);
                uint2v f2 = pl16swap(s2.x, s2.y);
                a1.x = f2.x; a1.z = f2.y;
            }
            {   // dw = 1
                uint2v s1 = pl32swap(Dw[mg][0][1], Dw[mg][1][1]);
                uint2v f1 = pl16swap(s1.x, s1.y);
                a0.y = f1.x; a0.w = f1.y;
                uint2v s2 = pl32swap(Dw[mg][2][1], Dw[mg][3][1]);
                uint2v f2 = pl16swap(s2.x, s2.y);
                a1.y = f2.x; a1.w = f2.y;
            }
            pa[mg][0] = __builtin_bit_cast(short8, a0);
            pa[mg][1] = __builtin_bit_cast(short8, a1);
            lacc[mg] = __builtin_amdgcn_mfma_f32_16x16x32_bf16(pa[mg][0], ones8, lacc[mg], 0, 0, 0);
            lacc[mg] = __builtin_amdgcn_mfma_f32_16x16x32_bf16(pa[mg][1], ones8, lacc[mg], 0, 0, 0);
        }

        // O += P @ V
        __builtin_amdgcn_s_setprio(1);
        #pragma unroll
        for (int dt = 0; dt < 4; dt++) {
            const int d = dt * 16 + l16;
            short8 vb0 = *(const short8*)&Vts[cur][d * 64 + ((quad ^ (d & 7)) * 8)];
            short8 vb1 = *(const short8*)&Vts[cur][d * 64 + (((4 + quad) ^ (d & 7)) * 8)];
            #pragma unroll
            for (int mg = 0; mg < 2; mg++) {
                o[mg][dt] = __builtin_amdgcn_mfma_f32_16x16x32_bf16(pa[mg][0], vb0, o[mg][dt], 0, 0, 0);
                o[mg][dt] = __builtin_amdgcn_mfma_f32_16x16x32_bf16(pa[mg][1], vb1, o[mg][dt], 0, 0, 0);
            }
        }
        __builtin_amdgcn_s_setprio(0);

        if (jt < 31) ATTN_WRITE(cur ^ 1);
    }

    // Normalize + store bf16.
    #pragma unroll
    for (int mg = 0; mg < 2; mg++) {
        #pragma unroll
        for (int r = 0; r < 4; r++) {
            const float inv_l = 1.0f / lacc[mg][r];
            const size_t row = (size_t)(b * SEQ + q0 + 32 * wave + mg * 16 + quad * 4 + r);
            #pragma unroll
            for (int dt = 0; dt < 4; dt++) {
                attn_out[row * FEAT + h * 64 + dt * 16 + l16] = (ushortT)f2bf(o[mg][dt][r] * inv_l);
            }
        }
    }
#undef ATTN_ISSUE
#undef ATTN_WRITE
}

// ---------------------------------------------------------------------------
// Launch
// ---------------------------------------------------------------------------
extern "C" void kernel_launch(void* const* d_in, const int* in_sizes, int n_in,
                              void* d_out, int out_size, void* d_ws, size_t ws_size,
                              hipStream_t stream)
{
    const float* x      = (const float*)d_in[0];
    const int*   mask   = (const int*)d_in[1];
    const float* alpha1 = (const float*)d_in[2];
    const float* bias1  = (const float*)d_in[3];
    const float* alpha2 = (const float*)d_in[4];
    const float* bias2  = (const float*)d_in[5];
    const float* Wq     = (const float*)d_in[6];
    const float* bq     = (const float*)d_in[7];
    const float* Wk     = (const float*)d_in[8];
    const float* bk     = (const float*)d_in[9];
    const float* Wv     = (const float*)d_in[10];
    const float* bv     = (const float*)d_in[11];
    const float* Wo     = (const float*)d_in[12];
    const float* bo     = (const float*)d_in[13];
    const float* W1     = (const float*)d_in[14];
    const float* b1     = (const float*)d_in[15];
    const float* W2     = (const float*)d_in[16];
    const float* b2     = (const float*)d_in[17];
    float* out = (float*)d_out;

    char* ws = (char*)d_ws;
    const size_t MB = 1024 * 1024;
    ushortT* x2b    = (ushortT*)(ws);              // LN1 out; attn out later
    ushortT* attn_o = (ushortT*)(ws);
    ushortT* qkv    = (ushortT*)(ws + 16 * MB);    // fused q|k|v
    ushortT* x2b2   = (ushortT*)(ws + 16 * MB);    // LN2 out (after attn)
    ushortT* hbuf   = (ushortT*)(ws + 32 * MB);    // FF hidden
    ushortT* vtb    = (ushortT*)(ws + 64 * MB);
    ushortT* Wqkvt  = (ushortT*)(ws + 80 * MB);    // 6 MB  [3072][1024]
    ushortT* Wot    = (ushortT*)(ws + 86 * MB);    // 2 MB
    ushortT* W1t    = (ushortT*)(ws + 88 * MB);    // 1 MB  [512][1024]
    ushortT* W2t    = (ushortT*)(ws + 89 * MB);    // 1 MB  [1024][512]
    float*   b1p    = (float*)  (ws + 90 * MB);
    float*   bqkv   = (float*)  (ws + 90 * MB + 16384);
    unsigned int* mbits = (unsigned int*)(ws + 91 * MB); // 2 MB

    const dim3 blk(256);

    // Prep (1 launch) + mask pack
    prep_kernel<<<1281, blk, 0, stream>>>(Wq, Wk, Wv, Wo, W1, W2, bq, bk, bv, b1,
                                          Wqkvt, Wot, W1t, W2t, bqkv, b1p);
    maskbits_kernel<<<(BATCH * SEQ * SEQ) / 256, blk, 0, stream>>>(mask, mbits);

    // 1. LN1 -> bf16
    ln_kernel<<<ROWS, blk, 0, stream>>>(x, alpha1, bias1, x2b);

    // 2. Fused QKV projection
    mfma_gemm<0, 0, 1, 128><<<dim3(24, 64), blk, 0, stream>>>(
        x2b, Wqkvt, bqkv, nullptr, qkv, ROWS, QKVSTR, FEAT);

    // 3. V transpose + flash attention
    transpose_v_kernel<<<BATCH * HEADS * (SEQ / 64), blk, 0, stream>>>(qkv + 2048, vtb);
    mfma_attn<<<BATCH * HEADS * (SEQ / AQ), blk, 0, stream>>>(qkv, vtb, mbits, attn_o);

    // 4. out = x + attn @ Wo + bo
    mfma_gemm<0, 1, 0, 128><<<dim3(8, 64), blk, 0, stream>>>(
        attn_o, Wot, bo, x, out, ROWS, FEAT, FEAT);

    // 5. LN2 -> bf16
    ln_kernel<<<ROWS, blk, 0, stream>>>(out, alpha2, bias2, x2b2);

    // 6. h = ELU(x2b2 @ W1 + b1)
    mfma_gemm<1, 0, 1, 64><<<dim3(FFP / 64, 64), blk, 0, stream>>>(
        x2b2, W1t, b1p, nullptr, hbuf, ROWS, FFP, FEAT);

    // 7. out += h @ W2 + b2
    mfma_gemm<0, 1, 0, 128><<<dim3(8, 64), blk, 0, stream>>>(
        hbuf, W2t, b2, out, out, ROWS, FEAT, FFP);
}

// Round 4
// 479.689 us; speedup vs baseline: 1.2748x; 1.0126x over previous
//
#include <hip/hip_runtime.h>
#include <hip/hip_bf16.h>
#include <math.h>

// Problem constants
#define BATCH 4
#define SEQ 2048
#define FEAT 1024
#define HEADS 16
#define HDIM 64
#define FF 500
#define FFP 512                 // FF padded to multiple of 128
#define ROWS (BATCH * SEQ)      // 8192
#define QKVSTR 3072             // fused q|k|v row stride
#define AQ 128                  // attn q-rows per block

typedef unsigned short ushortT;
typedef __attribute__((ext_vector_type(8))) short short8;   // 8 bf16 (4 VGPRs)
typedef __attribute__((ext_vector_type(4))) float floatx4;  // MFMA acc
typedef __attribute__((ext_vector_type(2))) unsigned int uint2v;
typedef __attribute__((ext_vector_type(4))) unsigned int uint4v;

#if defined(__has_builtin) && __has_builtin(__builtin_amdgcn_exp2f)
#define EXP2F(x) __builtin_amdgcn_exp2f(x)
#else
#define EXP2F(x) exp2f(x)
#endif

#if defined(__has_builtin)
#if __has_builtin(__builtin_amdgcn_permlane32_swap) && __has_builtin(__builtin_amdgcn_permlane16_swap)
#define HAVE_PLSWAP 1
#endif
#endif

__device__ __forceinline__ unsigned int f2bf(float f) {
    unsigned int u = __builtin_bit_cast(unsigned int, f);
    u += 0x7fffu + ((u >> 16) & 1u);           // RNE
    return (u >> 16) & 0xffffu;
}
__device__ __forceinline__ float bf2f(short b) {
    unsigned int u = ((unsigned int)(unsigned short)b) << 16;
    return __builtin_bit_cast(float, u);
}
// pack two f32 -> one dword of 2x bf16 (RNE) via the HW packed converter
// (v_cvt_pk_bf16_f32). Round 3 used a manual bit-trick here: ~10 VALU insts
// per dword vs 1 -- that alone was the 125->142us regression. memcpy (not
// bit_cast: __hip_bfloat162 is not trivially copyable; not a union: round-2
// unions went to scratch) extracts the dword; SROA promotes a 4B copy.
__device__ __forceinline__ unsigned int packbf2(float lo, float hi) {
    __hip_bfloat162 b2 = __float22bfloat162_rn(make_float2(lo, hi));
    unsigned int u;
    __builtin_memcpy(&u, &b2, 4);
    return u;
}

__device__ __forceinline__ unsigned int laneid() {
    return __builtin_amdgcn_mbcnt_hi(~0u, __builtin_amdgcn_mbcnt_lo(~0u, 0u));
}

// permlane32_swap semantics: ret.x = {a[0:32) ; b[0:32) moved to upper},
//                            ret.y = {a[32:64) moved to lower ; b[32:64)}
__device__ __forceinline__ uint2v pl32swap(unsigned int a, unsigned int b) {
#ifdef HAVE_PLSWAP
    return __builtin_amdgcn_permlane32_swap(a, b, false, false);
#else
    const unsigned int ln = laneid();
    unsigned int sa = (unsigned int)__shfl_xor((int)a, 32);
    unsigned int sb = (unsigned int)__shfl_xor((int)b, 32);
    uint2v r;
    r.x = (ln & 32) ? sb : a;
    r.y = (ln & 32) ? b : sa;
    return r;
#endif
}

// permlane16_swap semantics (per 32-half): ret.x = {a rows 0 ; b rows 0 -> 1},
//                                          ret.y = {a rows 1 -> 0 ; b rows 1}
__device__ __forceinline__ uint2v pl16swap(unsigned int a, unsigned int b) {
#ifdef HAVE_PLSWAP
    return __builtin_amdgcn_permlane16_swap(a, b, false, false);
#else
    const unsigned int ln = laneid();
    unsigned int sa = (unsigned int)__shfl_xor((int)a, 16);
    unsigned int sb = (unsigned int)__shfl_xor((int)b, 16);
    uint2v r;
    r.x = (ln & 16) ? sb : a;
    r.y = (ln & 16) ? b : sa;
    return r;
#endif
}

__device__ __forceinline__ void async16(void* lds, const void* g) {
    __builtin_amdgcn_global_load_lds(
        (const __attribute__((address_space(1))) unsigned int*)g,
        (__attribute__((address_space(3))) unsigned int*)lds, 16, 0, 0);
}

// ---------------------------------------------------------------------------
// Unified prep: 6 weight transpose+convert tiles + bias concat/pad.
// Blocks 0..1023: Wq/Wk/Wv/Wo (256 tiles each); 1024..1151: W1; 1152..1279: W2;
// 1280: biases.
// ---------------------------------------------------------------------------
__global__ void prep_kernel(const float* __restrict__ Wq, const float* __restrict__ Wk,
                            const float* __restrict__ Wv, const float* __restrict__ Wo,
                            const float* __restrict__ W1, const float* __restrict__ W2,
                            const float* __restrict__ bq, const float* __restrict__ bk,
                            const float* __restrict__ bv, const float* __restrict__ b1,
                            ushortT* __restrict__ Wqkvt, ushortT* __restrict__ Wot,
                            ushortT* __restrict__ W1t, ushortT* __restrict__ W2t,
                            float* __restrict__ bqkv, float* __restrict__ b1p)
{
    const int t = blockIdx.x;
    const int tid = threadIdx.x;
    if (t == 1280) {
        for (int i = tid; i < QKVSTR; i += 256)
            bqkv[i] = (i < 1024) ? bq[i] : ((i < 2048) ? bk[i - 1024] : bv[i - 2048]);
        for (int i = tid; i < FFP; i += 256)
            b1p[i] = (i < FF) ? b1[i] : 0.0f;
        return;
    }
    const float* W; ushortT* Wt; int K, N, Kp, bx, by;
    if (t < 1024) {
        const int wi = t >> 8, lt = t & 255;
        bx = lt & 15; by = lt >> 4; K = FEAT; N = FEAT; Kp = FEAT;
        W  = (wi == 0) ? Wq : (wi == 1) ? Wk : (wi == 2) ? Wv : Wo;
        Wt = (wi == 3) ? Wot : (Wqkvt + (size_t)wi * FEAT * FEAT);
    } else if (t < 1152) {
        const int lt = t - 1024; bx = lt & 7; by = lt >> 3;
        K = FEAT; N = FF; Kp = FEAT; W = W1; Wt = W1t;
    } else {
        const int lt = t - 1152; bx = lt & 15; by = lt >> 4;
        K = FF; N = FEAT; Kp = FFP; W = W2; Wt = W2t;
    }

    __shared__ float T[64][65];
    const int n0 = bx * 64, k0 = by * 64;
    const int r = tid >> 4;            // 0..15
    const int c = (tid & 15) * 4;      // 0..60
    #pragma unroll
    for (int i = 0; i < 4; i++) {
        const int kk = k0 + r + i * 16;
        #pragma unroll
        for (int e = 0; e < 4; e++) {
            const int nn = n0 + c + e;
            T[r + i * 16][c + e] = (kk < K && nn < N) ? W[(size_t)kk * N + nn] : 0.0f;
        }
    }
    __syncthreads();
    #pragma unroll
    for (int i = 0; i < 4; i++) {
        const int nn = r + i * 16;
        ushort4 o;
        o.x = (ushortT)f2bf(T[c + 0][nn]);
        o.y = (ushortT)f2bf(T[c + 1][nn]);
        o.z = (ushortT)f2bf(T[c + 2][nn]);
        o.w = (ushortT)f2bf(T[c + 3][nn]);
        *(ushort4*)(Wt + (size_t)(n0 + nn) * Kp + k0 + c) = o;
    }
}
// note: W1t has 512 rows allocated; rows 500..511 get zeros (T[][]=0 there),
// which is exactly the padding we want.

// ---------------------------------------------------------------------------
// Mask bit-pack: int32 0/1 [B,S,S] -> bitmask dwords [B,S,S/32].
// ---------------------------------------------------------------------------
__global__ void maskbits_kernel(const int* __restrict__ mask,
                                unsigned int* __restrict__ bits)
{
    const size_t g = (size_t)blockIdx.x * 256 + threadIdx.x;
    const int lane = threadIdx.x & 63;
    const unsigned long long bal = __ballot(mask[g] != 0);
    if (lane == 0)  bits[g >> 5] = (unsigned int)bal;
    if (lane == 32) bits[g >> 5] = (unsigned int)(bal >> 32);
}

// ---------------------------------------------------------------------------
// LayerNorm -> bf16. One block per row; wave-shuffle reduction, 1 barrier.
// ---------------------------------------------------------------------------
__global__ void ln_kernel(const float* __restrict__ x,
                          const float* __restrict__ alpha,
                          const float* __restrict__ bias,
                          ushortT* __restrict__ out)
{
    __shared__ float p1[4], p2[4];
    const int row = blockIdx.x;
    const int tid = threadIdx.x;
    const int wave = tid >> 6, lane = tid & 63;
    float4 v = ((const float4*)(x + (size_t)row * FEAT))[tid];

    float s1 = v.x + v.y + v.z + v.w;
    float s2 = v.x * v.x + v.y * v.y + v.z * v.z + v.w * v.w;
    #pragma unroll
    for (int off = 32; off > 0; off >>= 1) {
        s1 += __shfl_xor(s1, off);
        s2 += __shfl_xor(s2, off);
    }
    if (lane == 0) { p1[wave] = s1; p2[wave] = s2; }
    __syncthreads();
    const float t1 = p1[0] + p1[1] + p1[2] + p1[3];
    const float t2 = p2[0] + p2[1] + p2[2] + p2[3];
    const float mean = t1 * (1.0f / 1024.0f);
    const float var = fmaxf(t2 - 1024.0f * mean * mean, 0.0f) * (1.0f / 1023.0f);
    const float inv = 1.0f / (sqrtf(var) + 1e-6f);

    const float4 a = ((const float4*)alpha)[tid];
    const float4 b = ((const float4*)bias)[tid];
    ushort4 o;
    o.x = (ushortT)f2bf(a.x * (v.x - mean) * inv + b.x);
    o.y = (ushortT)f2bf(a.y * (v.y - mean) * inv + b.y);
    o.z = (ushortT)f2bf(a.z * (v.z - mean) * inv + b.z);
    o.w = (ushortT)f2bf(a.w * (v.w - mean) * inv + b.w);
    ((ushort4*)(out + (size_t)row * FEAT))[tid] = o;
}

// ---------------------------------------------------------------------------
// bf16 MFMA GEMM, BK=64 as two 32-K planes (keeps 64B LDS rows: conflict-free).
// 128xBN tile (BN=128: 2x2 waves, 4x4 frags; BN=64: 4x1 waves, 2x4 frags).
// ---------------------------------------------------------------------------
template<int ACT, int RES, int OUT_BF16, int BN>
__global__ __launch_bounds__(256)
void mfma_gemm(const ushortT* __restrict__ A, const ushortT* __restrict__ Bt,
               const float* __restrict__ bias, const float* __restrict__ R,
               void* __restrict__ Cout, int M, int N, int K)
{
    constexpr int MT = (BN == 128) ? 4 : 2;
    constexpr int MSPAN = (BN == 128) ? 64 : 32;
    __shared__ ushortT As[2][128 * 32];
    __shared__ ushortT Bs[2][BN * 32];

    const int tid  = threadIdx.x;
    const int wave = tid >> 6, lane = tid & 63;
    const int quad = lane >> 4, l16 = lane & 15;
    const int wm = (BN == 128) ? (wave >> 1) : wave;
    const int wn = (BN == 128) ? (wave & 1) : 0;
    const int row0 = blockIdx.y * 128, col0 = blockIdx.x * BN;

    const floatx4 z4 = {0.f, 0.f, 0.f, 0.f};
    floatx4 acc[MT][4];
    #pragma unroll
    for (int i = 0; i < MT; i++)
        #pragma unroll
        for (int j = 0; j < 4; j++) acc[i][j] = z4;

    for (int k0 = 0; k0 < K; k0 += 64) {
        __syncthreads();
        #pragma unroll
        for (int kh = 0; kh < 2; kh++) {
            #pragma unroll
            for (int i = 0; i < 2; i++) {
                const int rbase = 16 * (wave + 4 * i);
                const int r = rbase + (lane >> 2);
                const int co = (lane & 3) * 8;
                async16((char*)As[kh] + rbase * 64,
                        A + (size_t)(row0 + r) * K + k0 + kh * 32 + co);
            }
            if (BN == 128) {
                #pragma unroll
                for (int i = 0; i < 2; i++) {
                    const int rbase = 16 * (wave + 4 * i);
                    const int r = rbase + (lane >> 2);
                    const int co = (lane & 3) * 8;
                    async16((char*)Bs[kh] + rbase * 64,
                            Bt + (size_t)(col0 + r) * K + k0 + kh * 32 + co);
                }
            } else {
                const int rbase = 16 * wave;
                const int r = rbase + (lane >> 2);
                const int co = (lane & 3) * 8;
                async16((char*)Bs[kh] + rbase * 64,
                        Bt + (size_t)(col0 + r) * K + k0 + kh * 32 + co);
            }
        }
        __syncthreads();

        #pragma unroll
        for (int kh = 0; kh < 2; kh++) {
            short8 af[MT], bf[4];
            #pragma unroll
            for (int mt = 0; mt < MT; mt++)
                af[mt] = *(const short8*)&As[kh][(MSPAN * wm + 16 * mt + l16) * 32 + quad * 8];
            #pragma unroll
            for (int nt = 0; nt < 4; nt++)
                bf[nt] = *(const short8*)&Bs[kh][(64 * wn + 16 * nt + l16) * 32 + quad * 8];
            #pragma unroll
            for (int mt = 0; mt < MT; mt++)
                #pragma unroll
                for (int nt = 0; nt < 4; nt++)
                    acc[mt][nt] = __builtin_amdgcn_mfma_f32_16x16x32_bf16(
                        af[mt], bf[nt], acc[mt][nt], 0, 0, 0);
        }
    }

    #pragma unroll
    for (int mt = 0; mt < MT; mt++) {
        #pragma unroll
        for (int nt = 0; nt < 4; nt++) {
            const int col = col0 + 64 * wn + 16 * nt + l16;
            #pragma unroll
            for (int r = 0; r < 4; r++) {
                const int row = row0 + MSPAN * wm + 16 * mt + quad * 4 + r;
                float val = acc[mt][nt][r] + bias[col];
                if (ACT == 1) val = (val > 0.0f) ? val : (__expf(val) - 1.0f);
                if (RES) val += R[(size_t)row * N + col];
                if (OUT_BF16)
                    ((ushortT*)Cout)[(size_t)row * N + col] = (ushortT)f2bf(val);
                else
                    ((float*)Cout)[(size_t)row * N + col] = val;
            }
        }
    }
}

// ---------------------------------------------------------------------------
// V transpose: v bf16 (rows stride QKVSTR) -> vt bf16 [B][H][64 d][SEQ j]
// ---------------------------------------------------------------------------
__global__ void transpose_v_kernel(const ushortT* __restrict__ v, ushortT* __restrict__ vt)
{
    __shared__ ushortT T[64][80];
    const int bid = blockIdx.x;
    const int jt = bid & 31, h = (bid >> 5) & 15, b = bid >> 9;
    const int j0 = jt * 64;
    const int tid = threadIdx.x;

    const int j = tid >> 2;
    #pragma unroll
    for (int i = 0; i < 2; i++) {
        const int c = (tid & 3) * 2 + i;
        short8 val = *(const short8*)(v + (size_t)(b * SEQ + j0 + j) * QKVSTR + h * 64 + c * 8);
        *(short8*)&T[j][c * 8] = val;
    }
    __syncthreads();
    const int d = tid >> 2;
    #pragma unroll
    for (int i = 0; i < 2; i++) {
        const int cj = (tid & 3) * 2 + i;
        short8 tmp;
        #pragma unroll
        for (int e = 0; e < 8; e++) tmp[e] = (short)T[cj * 8 + e][d];
        *(short8*)(vt + ((size_t)((b * HEADS + h) * 64 + d)) * SEQ + j0 + cj * 8) = tmp;
    }
}

// ---------------------------------------------------------------------------
// MFMA flash attention: 128 q-rows/block, 64-j tiles, no-max softmax, S^T
// form, dbuf K/V staging, one barrier/tile. P redistribution for the PV
// A-fragment is done fully in-register via permlane16/32_swap (no Ps LDS):
// lane (l16,q) holds P[m=l16][j=16nt+4q+r]; PV needs j=8q+i (pa0) and
// 32+8q+i (pa1). Per dword pair: PL32(D[even nt],D[odd nt]) then PL16
// lands exactly the fragment dwords. All temporaries are scalars/ext-vectors
// (NO unions -- round-2 unions went to scratch: 690 MB spill traffic).
// bf16 pack via v_cvt_pk (round-3 manual bit-trick cost 17us of VALU).
// LDS = 32KB -> 4 blocks/CU resident (grid-capped).
// ---------------------------------------------------------------------------
__global__ __launch_bounds__(256)
void mfma_attn(const ushortT* __restrict__ qkv, const ushortT* __restrict__ vt,
               const unsigned int* __restrict__ mbits, ushortT* __restrict__ attn_out)
{
    __shared__ ushortT Ks[2][64 * 64];    // [j][d] swizzled
    __shared__ ushortT Vts[2][64 * 64];   // [d][j] swizzled

    const int tid = threadIdx.x;
    const int wave = tid >> 6, lane = tid & 63;
    const int quad = lane >> 4, l16 = lane & 15;
    const int bid = blockIdx.x;
    const int qt = bid & 15, h = (bid >> 4) & 15, b = bid >> 8;
    const int q0 = qt * AQ;

    const ushortT* qptr = qkv;
    const ushortT* kptr = qkv + 1024;

    // Q fragments for both m-groups, pre-scaled by log2(e)/8.
    short8 qf[2][2];
    #pragma unroll
    for (int mg = 0; mg < 2; mg++) {
        const size_t qrow = (size_t)(b * SEQ + q0 + 32 * wave + mg * 16 + l16);
        short8 t0 = *(const short8*)(qptr + qrow * QKVSTR + h * 64 + quad * 8);
        short8 t1 = *(const short8*)(qptr + qrow * QKVSTR + h * 64 + 32 + quad * 8);
        const float cs = 0.125f * 1.4426950408889634f;
        #pragma unroll
        for (int i = 0; i < 8; i++) {
            qf[mg][0][i] = (short)f2bf(bf2f(t0[i]) * cs);
            qf[mg][1][i] = (short)f2bf(bf2f(t1[i]) * cs);
        }
    }

    short8 ones8;
    #pragma unroll
    for (int i = 0; i < 8; i++) ones8[i] = (short)0x3F80;  // bf16 1.0

    const floatx4 z4 = {0.f, 0.f, 0.f, 0.f};
    floatx4 o[2][4];
    #pragma unroll
    for (int mg = 0; mg < 2; mg++)
        #pragma unroll
        for (int dt = 0; dt < 4; dt++) o[mg][dt] = z4;
    floatx4 lacc[2] = {z4, z4};

    // staging pointers (advance per tile)
    const int rr = tid >> 2;
    const int c0 = (tid & 3) * 2;
    const ushortT* gk = kptr + (size_t)(b * SEQ + rr) * QKVSTR + h * 64;
    const ushortT* gv = vt + ((size_t)((b * HEADS + h) * 64 + rr)) * SEQ;
    short8 rk0, rk1, rv0, rv1;

#define ATTN_ISSUE() {                                                       \
    rk0 = *(const short8*)(gk + c0 * 8);                                     \
    rk1 = *(const short8*)(gk + c0 * 8 + 8);                                 \
    rv0 = *(const short8*)(gv + c0 * 8);                                     \
    rv1 = *(const short8*)(gv + c0 * 8 + 8);                                 \
    gk += (size_t)64 * QKVSTR; gv += 64; }

#define ATTN_WRITE(BI) {                                                     \
    *(short8*)&Ks[BI][rr * 64 + ((c0 ^ (rr & 7)) * 8)] = rk0;                \
    *(short8*)&Ks[BI][rr * 64 + (((c0 + 1) ^ (rr & 7)) * 8)] = rk1;          \
    *(short8*)&Vts[BI][rr * 64 + ((c0 ^ (rr & 7)) * 8)] = rv0;               \
    *(short8*)&Vts[BI][rr * 64 + (((c0 + 1) ^ (rr & 7)) * 8)] = rv1; }

    const unsigned int* mrowp[2];
    mrowp[0] = mbits + (size_t)(b * SEQ + q0 + 32 * wave + l16) * (SEQ / 32);
    mrowp[1] = mrowp[0] + 16 * (SEQ / 32);

    // Prologue: stage tile 0
    ATTN_ISSUE();
    ATTN_WRITE(0);

    #pragma unroll 2
    for (int jt = 0; jt < 32; jt++) {
        __syncthreads();
        const int cur = jt & 1;
        unsigned int w[2][2];
        #pragma unroll
        for (int mg = 0; mg < 2; mg++) {
            w[mg][0] = mrowp[mg][jt * 2];
            w[mg][1] = mrowp[mg][jt * 2 + 1];
        }
        if (jt < 31) ATTN_ISSUE();

        // S^T = K @ Q^T for both m-groups (K frags read once)
        floatx4 st[2][4];
        __builtin_amdgcn_s_setprio(1);
        #pragma unroll
        for (int nt = 0; nt < 4; nt++) {
            const int j = nt * 16 + l16;
            short8 ka0 = *(const short8*)&Ks[cur][j * 64 + ((quad ^ (j & 7)) * 8)];
            short8 ka1 = *(const short8*)&Ks[cur][j * 64 + (((4 + quad) ^ (j & 7)) * 8)];
            #pragma unroll
            for (int mg = 0; mg < 2; mg++) {
                floatx4 t = z4;
                t = __builtin_amdgcn_mfma_f32_16x16x32_bf16(ka0, qf[mg][0], t, 0, 0, 0);
                t = __builtin_amdgcn_mfma_f32_16x16x32_bf16(ka1, qf[mg][1], t, 0, 0, 0);
                st[mg][nt] = t;
            }
        }
        __builtin_amdgcn_s_setprio(0);

        // softmax: p = exp2(masked ? 0 : s); pack to bf16-pair dwords per nt.
        // Dw[mg][nt][dw] = bf16pair(p[2dw], p[2dw+1]) for j = 16nt+4quad+{..}
        unsigned int Dw[2][4][2];
        #pragma unroll
        for (int mg = 0; mg < 2; mg++) {
            #pragma unroll
            for (int nt = 0; nt < 4; nt++) {
                const unsigned int ww = (nt & 2) ? w[mg][1] : w[mg][0];
                const unsigned int wsh = ww >> ((nt & 1) * 16 + quad * 4);
                float p0 = EXP2F((wsh & 1u) ? st[mg][nt][0] : 0.0f);
                float p1 = EXP2F((wsh & 2u) ? st[mg][nt][1] : 0.0f);
                float p2 = EXP2F((wsh & 4u) ? st[mg][nt][2] : 0.0f);
                float p3 = EXP2F((wsh & 8u) ? st[mg][nt][3] : 0.0f);
                Dw[mg][nt][0] = packbf2(p0, p1);
                Dw[mg][nt][1] = packbf2(p2, p3);
            }
        }

        // In-register redistribution to PV A-fragments.
        // After PL32(D[e][dw], D[o][dw]):  x: Q0=s0.De Q1=s1.De Q2=s0.Do Q3=s1.Do
        //                                  y: Q0=s2.De Q1=s3.De Q2=s2.Do Q3=s3.Do
        // After PL16(x, y):                x: Q0=s0.De Q1=s2.De Q2=s0.Do Q3=s2.Do
        //                                  y: Q0=s1.De Q1=s3.De Q2=s1.Do Q3=s3.Do
        // which are exactly pa dwords {dw} and {2+dw}.
        short8 pa[2][2];
        #pragma unroll
        for (int mg = 0; mg < 2; mg++) {
            uint4v a0, a1;
            {   // dw = 0
                uint2v s1 = pl32swap(Dw[mg][0][0], Dw[mg][1][0]);
                uint2v f1 = pl16swap(s1.x, s1.y);
                a0.x = f1.x; a0.z = f1.y;
                uint2v s2 = pl32swap(Dw[mg][2][0], Dw[mg][3][0]);
                uint2v f2 = pl16swap(s2.x, s2.y);
                a1.x = f2.x; a1.z = f2.y;
            }
            {   // dw = 1
                uint2v s1 = pl32swap(Dw[mg][0][1], Dw[mg][1][1]);
                uint2v f1 = pl16swap(s1.x, s1.y);
                a0.y = f1.x; a0.w = f1.y;
                uint2v s2 = pl32swap(Dw[mg][2][1], Dw[mg][3][1]);
                uint2v f2 = pl16swap(s2.x, s2.y);
                a1.y = f2.x; a1.w = f2.y;
            }
            pa[mg][0] = __builtin_bit_cast(short8, a0);
            pa[mg][1] = __builtin_bit_cast(short8, a1);
            lacc[mg] = __builtin_amdgcn_mfma_f32_16x16x32_bf16(pa[mg][0], ones8, lacc[mg], 0, 0, 0);
            lacc[mg] = __builtin_amdgcn_mfma_f32_16x16x32_bf16(pa[mg][1], ones8, lacc[mg], 0, 0, 0);
        }

        // O += P @ V
        __builtin_amdgcn_s_setprio(1);
        #pragma unroll
        for (int dt = 0; dt < 4; dt++) {
            const int d = dt * 16 + l16;
            short8 vb0 = *(const short8*)&Vts[cur][d * 64 + ((quad ^ (d & 7)) * 8)];
            short8 vb1 = *(const short8*)&Vts[cur][d * 64 + (((4 + quad) ^ (d & 7)) * 8)];
            #pragma unroll
            for (int mg = 0; mg < 2; mg++) {
                o[mg][dt] = __builtin_amdgcn_mfma_f32_16x16x32_bf16(pa[mg][0], vb0, o[mg][dt], 0, 0, 0);
                o[mg][dt] = __builtin_amdgcn_mfma_f32_16x16x32_bf16(pa[mg][1], vb1, o[mg][dt], 0, 0, 0);
            }
        }
        __builtin_amdgcn_s_setprio(0);

        if (jt < 31) ATTN_WRITE(cur ^ 1);
    }

    // Normalize + store bf16.
    #pragma unroll
    for (int mg = 0; mg < 2; mg++) {
        #pragma unroll
        for (int r = 0; r < 4; r++) {
            const float inv_l = 1.0f / lacc[mg][r];
            const size_t row = (size_t)(b * SEQ + q0 + 32 * wave + mg * 16 + quad * 4 + r);
            #pragma unroll
            for (int dt = 0; dt < 4; dt++) {
                attn_out[row * FEAT + h * 64 + dt * 16 + l16] = (ushortT)f2bf(o[mg][dt][r] * inv_l);
            }
        }
    }
#undef ATTN_ISSUE
#undef ATTN_WRITE
}

// ---------------------------------------------------------------------------
// Launch
// ---------------------------------------------------------------------------
extern "C" void kernel_launch(void* const* d_in, const int* in_sizes, int n_in,
                              void* d_out, int out_size, void* d_ws, size_t ws_size,
                              hipStream_t stream)
{
    const float* x      = (const float*)d_in[0];
    const int*   mask   = (const int*)d_in[1];
    const float* alpha1 = (const float*)d_in[2];
    const float* bias1  = (const float*)d_in[3];
    const float* alpha2 = (const float*)d_in[4];
    const float* bias2  = (const float*)d_in[5];
    const float* Wq     = (const float*)d_in[6];
    const float* bq     = (const float*)d_in[7];
    const float* Wk     = (const float*)d_in[8];
    const float* bk     = (const float*)d_in[9];
    const float* Wv     = (const float*)d_in[10];
    const float* bv     = (const float*)d_in[11];
    const float* Wo     = (const float*)d_in[12];
    const float* bo     = (const float*)d_in[13];
    const float* W1     = (const float*)d_in[14];
    const float* b1     = (const float*)d_in[15];
    const float* W2     = (const float*)d_in[16];
    const float* b2     = (const float*)d_in[17];
    float* out = (float*)d_out;

    char* ws = (char*)d_ws;
    const size_t MB = 1024 * 1024;
    ushortT* x2b    = (ushortT*)(ws);              // LN1 out; attn out later
    ushortT* attn_o = (ushortT*)(ws);
    ushortT* qkv    = (ushortT*)(ws + 16 * MB);    // fused q|k|v
    ushortT* x2b2   = (ushortT*)(ws + 16 * MB);    // LN2 out (after attn)
    ushortT* hbuf   = (ushortT*)(ws + 32 * MB);    // FF hidden
    ushortT* vtb    = (ushortT*)(ws + 64 * MB);
    ushortT* Wqkvt  = (ushortT*)(ws + 80 * MB);    // 6 MB  [3072][1024]
    ushortT* Wot    = (ushortT*)(ws + 86 * MB);    // 2 MB
    ushortT* W1t    = (ushortT*)(ws + 88 * MB);    // 1 MB  [512][1024]
    ushortT* W2t    = (ushortT*)(ws + 89 * MB);    // 1 MB  [1024][512]
    float*   b1p    = (float*)  (ws + 90 * MB);
    float*   bqkv   = (float*)  (ws + 90 * MB + 16384);
    unsigned int* mbits = (unsigned int*)(ws + 91 * MB); // 2 MB

    const dim3 blk(256);

    // Prep (1 launch) + mask pack
    prep_kernel<<<1281, blk, 0, stream>>>(Wq, Wk, Wv, Wo, W1, W2, bq, bk, bv, b1,
                                          Wqkvt, Wot, W1t, W2t, bqkv, b1p);
    maskbits_kernel<<<(BATCH * SEQ * SEQ) / 256, blk, 0, stream>>>(mask, mbits);

    // 1. LN1 -> bf16
    ln_kernel<<<ROWS, blk, 0, stream>>>(x, alpha1, bias1, x2b);

    // 2. Fused QKV projection
    mfma_gemm<0, 0, 1, 128><<<dim3(24, 64), blk, 0, stream>>>(
        x2b, Wqkvt, bqkv, nullptr, qkv, ROWS, QKVSTR, FEAT);

    // 3. V transpose + flash attention
    transpose_v_kernel<<<BATCH * HEADS * (SEQ / 64), blk, 0, stream>>>(qkv + 2048, vtb);
    mfma_attn<<<BATCH * HEADS * (SEQ / AQ), blk, 0, stream>>>(qkv, vtb, mbits, attn_o);

    // 4. out = x + attn @ Wo + bo
    mfma_gemm<0, 1, 0, 128><<<dim3(8, 64), blk, 0, stream>>>(
        attn_o, Wot, bo, x, out, ROWS, FEAT, FEAT);

    // 5. LN2 -> bf16
    ln_kernel<<<ROWS, blk, 0, stream>>>(out, alpha2, bias2, x2b2);

    // 6. h = ELU(x2b2 @ W1 + b1)
    mfma_gemm<1, 0, 1, 64><<<dim3(FFP / 64, 64), blk, 0, stream>>>(
        x2b2, W1t, b1p, nullptr, hbuf, ROWS, FFP, FEAT);

    // 7. out += h @ W2 + b2
    mfma_gemm<0, 1, 0, 128><<<dim3(8, 64), blk, 0, stream>>>(
        hbuf, W2t, b2, out, out, ROWS, FEAT, FFP);
}

// Round 5
// 466.501 us; speedup vs baseline: 1.3109x; 1.0283x over previous
//
#include <hip/hip_runtime.h>
#include <hip/hip_bf16.h>
#include <math.h>

// Problem constants
#define BATCH 4
#define SEQ 2048
#define FEAT 1024
#define HEADS 16
#define HDIM 64
#define FF 500
#define FFP 512                 // FF padded to multiple of 128
#define ROWS (BATCH * SEQ)      // 8192
#define QKVSTR 3072             // fused q|k|v row stride
#define AQ 128                  // attn q-rows per block

typedef unsigned short ushortT;
typedef __attribute__((ext_vector_type(8))) short short8;   // 8 bf16 (4 VGPRs)
typedef __attribute__((ext_vector_type(4))) float floatx4;  // MFMA acc

#if defined(__has_builtin) && __has_builtin(__builtin_amdgcn_exp2f)
#define EXP2F(x) __builtin_amdgcn_exp2f(x)
#else
#define EXP2F(x) exp2f(x)
#endif

__device__ __forceinline__ unsigned short f2bf(float f) {
    unsigned int u = __builtin_bit_cast(unsigned int, f);
    u += 0x7fffu + ((u >> 16) & 1u);           // RNE
    return (unsigned short)(u >> 16);
}
__device__ __forceinline__ float bf2f(short b) {
    unsigned int u = ((unsigned int)(unsigned short)b) << 16;
    return __builtin_bit_cast(float, u);
}

__device__ __forceinline__ void async16(void* lds, const void* g) {
    __builtin_amdgcn_global_load_lds(
        (const __attribute__((address_space(1))) unsigned int*)g,
        (__attribute__((address_space(3))) unsigned int*)lds, 16, 0, 0);
}

// ---------------------------------------------------------------------------
// Unified prep: 6 weight transpose+convert tiles + bias concat/pad.
// Blocks 0..1023: Wq/Wk/Wv/Wo (256 tiles each); 1024..1151: W1; 1152..1279: W2;
// 1280: biases.
// ---------------------------------------------------------------------------
__global__ void prep_kernel(const float* __restrict__ Wq, const float* __restrict__ Wk,
                            const float* __restrict__ Wv, const float* __restrict__ Wo,
                            const float* __restrict__ W1, const float* __restrict__ W2,
                            const float* __restrict__ bq, const float* __restrict__ bk,
                            const float* __restrict__ bv, const float* __restrict__ b1,
                            ushortT* __restrict__ Wqkvt, ushortT* __restrict__ Wot,
                            ushortT* __restrict__ W1t, ushortT* __restrict__ W2t,
                            float* __restrict__ bqkv, float* __restrict__ b1p)
{
    const int t = blockIdx.x;
    const int tid = threadIdx.x;
    if (t == 1280) {
        for (int i = tid; i < QKVSTR; i += 256)
            bqkv[i] = (i < 1024) ? bq[i] : ((i < 2048) ? bk[i - 1024] : bv[i - 2048]);
        for (int i = tid; i < FFP; i += 256)
            b1p[i] = (i < FF) ? b1[i] : 0.0f;
        return;
    }
    const float* W; ushortT* Wt; int K, N, Kp, bx, by;
    if (t < 1024) {
        const int wi = t >> 8, lt = t & 255;
        bx = lt & 15; by = lt >> 4; K = FEAT; N = FEAT; Kp = FEAT;
        W  = (wi == 0) ? Wq : (wi == 1) ? Wk : (wi == 2) ? Wv : Wo;
        Wt = (wi == 3) ? Wot : (Wqkvt + (size_t)wi * FEAT * FEAT);
    } else if (t < 1152) {
        const int lt = t - 1024; bx = lt & 7; by = lt >> 3;
        K = FEAT; N = FF; Kp = FEAT; W = W1; Wt = W1t;
    } else {
        const int lt = t - 1152; bx = lt & 15; by = lt >> 4;
        K = FF; N = FEAT; Kp = FFP; W = W2; Wt = W2t;
    }

    __shared__ float T[64][65];
    const int n0 = bx * 64, k0 = by * 64;
    const int r = tid >> 4;            // 0..15
    const int c = (tid & 15) * 4;      // 0..60
    #pragma unroll
    for (int i = 0; i < 4; i++) {
        const int kk = k0 + r + i * 16;
        #pragma unroll
        for (int e = 0; e < 4; e++) {
            const int nn = n0 + c + e;
            T[r + i * 16][c + e] = (kk < K && nn < N) ? W[(size_t)kk * N + nn] : 0.0f;
        }
    }
    __syncthreads();
    #pragma unroll
    for (int i = 0; i < 4; i++) {
        const int nn = r + i * 16;
        ushort4 o;
        o.x = f2bf(T[c + 0][nn]);
        o.y = f2bf(T[c + 1][nn]);
        o.z = f2bf(T[c + 2][nn]);
        o.w = f2bf(T[c + 3][nn]);
        *(ushort4*)(Wt + (size_t)(n0 + nn) * Kp + k0 + c) = o;
    }
}
// note: W1t has 512 rows allocated; rows 500..511 get zeros (T[][]=0 there),
// which is exactly the padding we want.

// ---------------------------------------------------------------------------
// Mask bit-pack: int32 0/1 [B,S,S] -> bitmask dwords [B,S,S/32].
// ---------------------------------------------------------------------------
__global__ void maskbits_kernel(const int* __restrict__ mask,
                                unsigned int* __restrict__ bits)
{
    const size_t g = (size_t)blockIdx.x * 256 + threadIdx.x;
    const int lane = threadIdx.x & 63;
    const unsigned long long bal = __ballot(mask[g] != 0);
    if (lane == 0)  bits[g >> 5] = (unsigned int)bal;
    if (lane == 32) bits[g >> 5] = (unsigned int)(bal >> 32);
}

// ---------------------------------------------------------------------------
// LayerNorm -> bf16. One block per row; wave-shuffle reduction, 1 barrier.
// ---------------------------------------------------------------------------
__global__ void ln_kernel(const float* __restrict__ x,
                          const float* __restrict__ alpha,
                          const float* __restrict__ bias,
                          ushortT* __restrict__ out)
{
    __shared__ float p1[4], p2[4];
    const int row = blockIdx.x;
    const int tid = threadIdx.x;
    const int wave = tid >> 6, lane = tid & 63;
    float4 v = ((const float4*)(x + (size_t)row * FEAT))[tid];

    float s1 = v.x + v.y + v.z + v.w;
    float s2 = v.x * v.x + v.y * v.y + v.z * v.z + v.w * v.w;
    #pragma unroll
    for (int off = 32; off > 0; off >>= 1) {
        s1 += __shfl_xor(s1, off);
        s2 += __shfl_xor(s2, off);
    }
    if (lane == 0) { p1[wave] = s1; p2[wave] = s2; }
    __syncthreads();
    const float t1 = p1[0] + p1[1] + p1[2] + p1[3];
    const float t2 = p2[0] + p2[1] + p2[2] + p2[3];
    const float mean = t1 * (1.0f / 1024.0f);
    const float var = fmaxf(t2 - 1024.0f * mean * mean, 0.0f) * (1.0f / 1023.0f);
    const float inv = 1.0f / (sqrtf(var) + 1e-6f);

    const float4 a = ((const float4*)alpha)[tid];
    const float4 b = ((const float4*)bias)[tid];
    ushort4 o;
    o.x = f2bf(a.x * (v.x - mean) * inv + b.x);
    o.y = f2bf(a.y * (v.y - mean) * inv + b.y);
    o.z = f2bf(a.z * (v.z - mean) * inv + b.z);
    o.w = f2bf(a.w * (v.w - mean) * inv + b.w);
    ((ushort4*)(out + (size_t)row * FEAT))[tid] = o;
}

// ---------------------------------------------------------------------------
// bf16 MFMA GEMM, BK=64 as two 32-K planes (keeps 64B LDS rows: conflict-free).
// 128xBN tile (BN=128: 2x2 waves, 4x4 frags; BN=64: 4x1 waves, 2x4 frags).
// ---------------------------------------------------------------------------
template<int ACT, int RES, int OUT_BF16, int BN>
__global__ __launch_bounds__(256)
void mfma_gemm(const ushortT* __restrict__ A, const ushortT* __restrict__ Bt,
               const float* __restrict__ bias, const float* __restrict__ R,
               void* __restrict__ Cout, int M, int N, int K)
{
    constexpr int MT = (BN == 128) ? 4 : 2;
    constexpr int MSPAN = (BN == 128) ? 64 : 32;
    __shared__ ushortT As[2][128 * 32];
    __shared__ ushortT Bs[2][BN * 32];

    const int tid  = threadIdx.x;
    const int wave = tid >> 6, lane = tid & 63;
    const int quad = lane >> 4, l16 = lane & 15;
    const int wm = (BN == 128) ? (wave >> 1) : wave;
    const int wn = (BN == 128) ? (wave & 1) : 0;
    const int row0 = blockIdx.y * 128, col0 = blockIdx.x * BN;

    const floatx4 z4 = {0.f, 0.f, 0.f, 0.f};
    floatx4 acc[MT][4];
    #pragma unroll
    for (int i = 0; i < MT; i++)
        #pragma unroll
        for (int j = 0; j < 4; j++) acc[i][j] = z4;

    for (int k0 = 0; k0 < K; k0 += 64) {
        __syncthreads();
        #pragma unroll
        for (int kh = 0; kh < 2; kh++) {
            #pragma unroll
            for (int i = 0; i < 2; i++) {
                const int rbase = 16 * (wave + 4 * i);
                const int r = rbase + (lane >> 2);
                const int co = (lane & 3) * 8;
                async16((char*)As[kh] + rbase * 64,
                        A + (size_t)(row0 + r) * K + k0 + kh * 32 + co);
            }
            if (BN == 128) {
                #pragma unroll
                for (int i = 0; i < 2; i++) {
                    const int rbase = 16 * (wave + 4 * i);
                    const int r = rbase + (lane >> 2);
                    const int co = (lane & 3) * 8;
                    async16((char*)Bs[kh] + rbase * 64,
                            Bt + (size_t)(col0 + r) * K + k0 + kh * 32 + co);
                }
            } else {
                const int rbase = 16 * wave;
                const int r = rbase + (lane >> 2);
                const int co = (lane & 3) * 8;
                async16((char*)Bs[kh] + rbase * 64,
                        Bt + (size_t)(col0 + r) * K + k0 + kh * 32 + co);
            }
        }
        __syncthreads();

        #pragma unroll
        for (int kh = 0; kh < 2; kh++) {
            short8 af[MT], bf[4];
            #pragma unroll
            for (int mt = 0; mt < MT; mt++)
                af[mt] = *(const short8*)&As[kh][(MSPAN * wm + 16 * mt + l16) * 32 + quad * 8];
            #pragma unroll
            for (int nt = 0; nt < 4; nt++)
                bf[nt] = *(const short8*)&Bs[kh][(64 * wn + 16 * nt + l16) * 32 + quad * 8];
            #pragma unroll
            for (int mt = 0; mt < MT; mt++)
                #pragma unroll
                for (int nt = 0; nt < 4; nt++)
                    acc[mt][nt] = __builtin_amdgcn_mfma_f32_16x16x32_bf16(
                        af[mt], bf[nt], acc[mt][nt], 0, 0, 0);
        }
    }

    #pragma unroll
    for (int mt = 0; mt < MT; mt++) {
        #pragma unroll
        for (int nt = 0; nt < 4; nt++) {
            const int col = col0 + 64 * wn + 16 * nt + l16;
            #pragma unroll
            for (int r = 0; r < 4; r++) {
                const int row = row0 + MSPAN * wm + 16 * mt + quad * 4 + r;
                float val = acc[mt][nt][r] + bias[col];
                if (ACT == 1) val = (val > 0.0f) ? val : (__expf(val) - 1.0f);
                if (RES) val += R[(size_t)row * N + col];
                if (OUT_BF16)
                    ((ushortT*)Cout)[(size_t)row * N + col] = f2bf(val);
                else
                    ((float*)Cout)[(size_t)row * N + col] = val;
            }
        }
    }
}

// ---------------------------------------------------------------------------
// V transpose: v bf16 (rows stride QKVSTR) -> vt bf16 [B][H][64 d][SEQ j]
// ---------------------------------------------------------------------------
__global__ void transpose_v_kernel(const ushortT* __restrict__ v, ushortT* __restrict__ vt)
{
    __shared__ ushortT T[64][80];
    const int bid = blockIdx.x;
    const int jt = bid & 31, h = (bid >> 5) & 15, b = bid >> 9;
    const int j0 = jt * 64;
    const int tid = threadIdx.x;

    const int j = tid >> 2;
    #pragma unroll
    for (int i = 0; i < 2; i++) {
        const int c = (tid & 3) * 2 + i;
        short8 val = *(const short8*)(v + (size_t)(b * SEQ + j0 + j) * QKVSTR + h * 64 + c * 8);
        *(short8*)&T[j][c * 8] = val;
    }
    __syncthreads();
    const int d = tid >> 2;
    #pragma unroll
    for (int i = 0; i < 2; i++) {
        const int cj = (tid & 3) * 2 + i;
        union { short8 v8; ushortT u[8]; } tmp;
        #pragma unroll
        for (int e = 0; e < 8; e++) tmp.u[e] = T[cj * 8 + e][d];
        *(short8*)(vt + ((size_t)((b * HEADS + h) * 64 + d)) * SEQ + j0 + cj * 8) = tmp.v8;
    }
}

// ---------------------------------------------------------------------------
// MFMA flash attention: 128 q-rows/block, 64-j tiles, no-max softmax, S^T
// form, dbuf K/V staging, one barrier/tile. Round-0 Ps-LDS data path
// (measured faster than both in-register permlane variants: 125.5 vs
// 134-142us -- the Ps ds-latency is hidden by 4 blocks/CU, the permlane
// chain is not free on the VALU-bound pipe). New vs round 0:
//   * XCD swizzle: bid = (hw&7)*128 | hw>>3 -- all 16 q-tiles of one head
//     land on the same XCD's L2 (shared 1MB K/V), cutting redundant fills.
//   * mask words prefetched one j-tile ahead (L2 latency cover).
//   * s_setprio(1) around the MFMA clusters (m191: attn +4-7%).
// ---------------------------------------------------------------------------
__global__ __launch_bounds__(256)
void mfma_attn(const ushortT* __restrict__ qkv, const ushortT* __restrict__ vt,
               const unsigned int* __restrict__ mbits, ushortT* __restrict__ attn_out)
{
    __shared__ ushortT Ks[2][64 * 64];    // [j][d] swizzled
    __shared__ ushortT Vts[2][64 * 64];   // [d][j] swizzled
    __shared__ ushortT Ps[AQ * 64];       // [m][j] swizzled, wave-private rows

    const int tid = threadIdx.x;
    const int wave = tid >> 6, lane = tid & 63;
    const int quad = lane >> 4, l16 = lane & 15;
    // XCD-aware bijective swizzle (grid=1024, 1024%8==0): hw%8 = XCD.
    const int bid = ((blockIdx.x & 7) << 7) | (blockIdx.x >> 3);
    const int qt = bid & 15, h = (bid >> 4) & 15, b = bid >> 8;
    const int q0 = qt * AQ;

    const ushortT* qptr = qkv;
    const ushortT* kptr = qkv + 1024;

    // Q fragments for both m-groups, pre-scaled by log2(e)/8.
    short8 qf[2][2];
    #pragma unroll
    for (int mg = 0; mg < 2; mg++) {
        const size_t qrow = (size_t)(b * SEQ + q0 + 32 * wave + mg * 16 + l16);
        short8 t0 = *(const short8*)(qptr + qrow * QKVSTR + h * 64 + quad * 8);
        short8 t1 = *(const short8*)(qptr + qrow * QKVSTR + h * 64 + 32 + quad * 8);
        const float cs = 0.125f * 1.4426950408889634f;
        #pragma unroll
        for (int i = 0; i < 8; i++) {
            qf[mg][0][i] = (short)f2bf(bf2f(t0[i]) * cs);
            qf[mg][1][i] = (short)f2bf(bf2f(t1[i]) * cs);
        }
    }

    short8 ones8;
    #pragma unroll
    for (int i = 0; i < 8; i++) ones8[i] = (short)0x3F80;  // bf16 1.0

    const floatx4 z4 = {0.f, 0.f, 0.f, 0.f};
    floatx4 o[2][4];
    #pragma unroll
    for (int mg = 0; mg < 2; mg++)
        #pragma unroll
        for (int dt = 0; dt < 4; dt++) o[mg][dt] = z4;
    floatx4 lacc[2] = {z4, z4};

    // staging pointers (advance per tile)
    const int rr = tid >> 2;
    const int c0 = (tid & 3) * 2;
    const ushortT* gk = kptr + (size_t)(b * SEQ + rr) * QKVSTR + h * 64;
    const ushortT* gv = vt + ((size_t)((b * HEADS + h) * 64 + rr)) * SEQ;
    short8 rk0, rk1, rv0, rv1;

#define ATTN_ISSUE() {                                                       \
    rk0 = *(const short8*)(gk + c0 * 8);                                     \
    rk1 = *(const short8*)(gk + c0 * 8 + 8);                                 \
    rv0 = *(const short8*)(gv + c0 * 8);                                     \
    rv1 = *(const short8*)(gv + c0 * 8 + 8);                                 \
    gk += (size_t)64 * QKVSTR; gv += 64; }

#define ATTN_WRITE(BI) {                                                     \
    *(short8*)&Ks[BI][rr * 64 + ((c0 ^ (rr & 7)) * 8)] = rk0;                \
    *(short8*)&Ks[BI][rr * 64 + (((c0 + 1) ^ (rr & 7)) * 8)] = rk1;          \
    *(short8*)&Vts[BI][rr * 64 + ((c0 ^ (rr & 7)) * 8)] = rv0;               \
    *(short8*)&Vts[BI][rr * 64 + (((c0 + 1) ^ (rr & 7)) * 8)] = rv1; }

    const unsigned int* mrowp[2];
    mrowp[0] = mbits + (size_t)(b * SEQ + q0 + 32 * wave + l16) * (SEQ / 32);
    mrowp[1] = mrowp[0] + 16 * (SEQ / 32);
    const int mloc0 = 32 * wave + l16;

    // Prologue: stage tile 0; preload mask words for tile 0.
    ATTN_ISSUE();
    ATTN_WRITE(0);
    unsigned int w[2][2];
    #pragma unroll
    for (int mg = 0; mg < 2; mg++) {
        w[mg][0] = mrowp[mg][0];
        w[mg][1] = mrowp[mg][1];
    }

    #pragma unroll 2
    for (int jt = 0; jt < 32; jt++) {
        __syncthreads();
        const int cur = jt & 1;
        unsigned int wn[2][2];
        if (jt < 31) {
            ATTN_ISSUE();
            #pragma unroll
            for (int mg = 0; mg < 2; mg++) {
                wn[mg][0] = mrowp[mg][jt * 2 + 2];
                wn[mg][1] = mrowp[mg][jt * 2 + 3];
            }
        }

        // S^T = K @ Q^T for both m-groups (K frags read once)
        floatx4 st[2][4];
        __builtin_amdgcn_s_setprio(1);
        #pragma unroll
        for (int nt = 0; nt < 4; nt++) {
            const int j = nt * 16 + l16;
            short8 ka0 = *(const short8*)&Ks[cur][j * 64 + ((quad ^ (j & 7)) * 8)];
            short8 ka1 = *(const short8*)&Ks[cur][j * 64 + (((4 + quad) ^ (j & 7)) * 8)];
            #pragma unroll
            for (int mg = 0; mg < 2; mg++) {
                floatx4 t = z4;
                t = __builtin_amdgcn_mfma_f32_16x16x32_bf16(ka0, qf[mg][0], t, 0, 0, 0);
                t = __builtin_amdgcn_mfma_f32_16x16x32_bf16(ka1, qf[mg][1], t, 0, 0, 0);
                st[mg][nt] = t;
            }
        }
        __builtin_amdgcn_s_setprio(0);

        // softmax: p = exp2(masked ? 0 : s); packed bf16 writes into Ps[m][j]
        #pragma unroll
        for (int mg = 0; mg < 2; mg++) {
            const int mloc = mloc0 + mg * 16;
            #pragma unroll
            for (int nt = 0; nt < 4; nt++) {
                const unsigned int ww = (nt & 2) ? w[mg][1] : w[mg][0];
                const unsigned int wsh = ww >> ((nt & 1) * 16 + quad * 4);
                float p[4];
                p[0] = EXP2F((wsh & 1u) ? st[mg][nt][0] : 0.0f);
                p[1] = EXP2F((wsh & 2u) ? st[mg][nt][1] : 0.0f);
                p[2] = EXP2F((wsh & 4u) ? st[mg][nt][2] : 0.0f);
                p[3] = EXP2F((wsh & 8u) ? st[mg][nt][3] : 0.0f);
                const int j0 = nt * 16 + quad * 4;
                const int chunk = (j0 >> 3) ^ (mloc & 7);
                const int ci = j0 & 7;
                ushortT* dst = &Ps[mloc * 64 + chunk * 8 + ci];
                *(__hip_bfloat162*)(dst)     = __float22bfloat162_rn(make_float2(p[0], p[1]));
                *(__hip_bfloat162*)(dst + 2) = __float22bfloat162_rn(make_float2(p[2], p[3]));
            }
        }

        // O += P @ V ; lacc += P @ ones  (Ps rows wave-private: no barrier)
        short8 pa[2][2];
        #pragma unroll
        for (int mg = 0; mg < 2; mg++) {
            const int mloc = mloc0 + mg * 16;
            pa[mg][0] = *(const short8*)&Ps[mloc * 64 + ((quad ^ (mloc & 7)) * 8)];
            pa[mg][1] = *(const short8*)&Ps[mloc * 64 + (((4 + quad) ^ (mloc & 7)) * 8)];
            lacc[mg] = __builtin_amdgcn_mfma_f32_16x16x32_bf16(pa[mg][0], ones8, lacc[mg], 0, 0, 0);
            lacc[mg] = __builtin_amdgcn_mfma_f32_16x16x32_bf16(pa[mg][1], ones8, lacc[mg], 0, 0, 0);
        }
        __builtin_amdgcn_s_setprio(1);
        #pragma unroll
        for (int dt = 0; dt < 4; dt++) {
            const int d = dt * 16 + l16;
            short8 vb0 = *(const short8*)&Vts[cur][d * 64 + ((quad ^ (d & 7)) * 8)];
            short8 vb1 = *(const short8*)&Vts[cur][d * 64 + (((4 + quad) ^ (d & 7)) * 8)];
            #pragma unroll
            for (int mg = 0; mg < 2; mg++) {
                o[mg][dt] = __builtin_amdgcn_mfma_f32_16x16x32_bf16(pa[mg][0], vb0, o[mg][dt], 0, 0, 0);
                o[mg][dt] = __builtin_amdgcn_mfma_f32_16x16x32_bf16(pa[mg][1], vb1, o[mg][dt], 0, 0, 0);
            }
        }
        __builtin_amdgcn_s_setprio(0);

        if (jt < 31) {
            ATTN_WRITE(cur ^ 1);
            #pragma unroll
            for (int mg = 0; mg < 2; mg++) {
                w[mg][0] = wn[mg][0];
                w[mg][1] = wn[mg][1];
            }
        }
    }

    // Normalize + store bf16.
    #pragma unroll
    for (int mg = 0; mg < 2; mg++) {
        #pragma unroll
        for (int r = 0; r < 4; r++) {
            const float inv_l = 1.0f / lacc[mg][r];
            const size_t row = (size_t)(b * SEQ + q0 + 32 * wave + mg * 16 + quad * 4 + r);
            #pragma unroll
            for (int dt = 0; dt < 4; dt++) {
                attn_out[row * FEAT + h * 64 + dt * 16 + l16] = f2bf(o[mg][dt][r] * inv_l);
            }
        }
    }
#undef ATTN_ISSUE
#undef ATTN_WRITE
}

// ---------------------------------------------------------------------------
// Launch
// ---------------------------------------------------------------------------
extern "C" void kernel_launch(void* const* d_in, const int* in_sizes, int n_in,
                              void* d_out, int out_size, void* d_ws, size_t ws_size,
                              hipStream_t stream)
{
    const float* x      = (const float*)d_in[0];
    const int*   mask   = (const int*)d_in[1];
    const float* alpha1 = (const float*)d_in[2];
    const float* bias1  = (const float*)d_in[3];
    const float* alpha2 = (const float*)d_in[4];
    const float* bias2  = (const float*)d_in[5];
    const float* Wq     = (const float*)d_in[6];
    const float* bq     = (const float*)d_in[7];
    const float* Wk     = (const float*)d_in[8];
    const float* bk     = (const float*)d_in[9];
    const float* Wv     = (const float*)d_in[10];
    const float* bv     = (const float*)d_in[11];
    const float* Wo     = (const float*)d_in[12];
    const float* bo     = (const float*)d_in[13];
    const float* W1     = (const float*)d_in[14];
    const float* b1     = (const float*)d_in[15];
    const float* W2     = (const float*)d_in[16];
    const float* b2     = (const float*)d_in[17];
    float* out = (float*)d_out;

    char* ws = (char*)d_ws;
    const size_t MB = 1024 * 1024;
    ushortT* x2b    = (ushortT*)(ws);              // LN1 out; attn out later
    ushortT* attn_o = (ushortT*)(ws);
    ushortT* qkv    = (ushortT*)(ws + 16 * MB);    // fused q|k|v
    ushortT* x2b2   = (ushortT*)(ws + 16 * MB);    // LN2 out (after attn)
    ushortT* hbuf   = (ushortT*)(ws + 32 * MB);    // FF hidden
    ushortT* vtb    = (ushortT*)(ws + 64 * MB);
    ushortT* Wqkvt  = (ushortT*)(ws + 80 * MB);    // 6 MB  [3072][1024]
    ushortT* Wot    = (ushortT*)(ws + 86 * MB);    // 2 MB
    ushortT* W1t    = (ushortT*)(ws + 88 * MB);    // 1 MB  [512][1024]
    ushortT* W2t    = (ushortT*)(ws + 89 * MB);    // 1 MB  [1024][512]
    float*   b1p    = (float*)  (ws + 90 * MB);
    float*   bqkv   = (float*)  (ws + 90 * MB + 16384);
    unsigned int* mbits = (unsigned int*)(ws + 91 * MB); // 2 MB

    const dim3 blk(256);

    // Prep (1 launch) + mask pack
    prep_kernel<<<1281, blk, 0, stream>>>(Wq, Wk, Wv, Wo, W1, W2, bq, bk, bv, b1,
                                          Wqkvt, Wot, W1t, W2t, bqkv, b1p);
    maskbits_kernel<<<(BATCH * SEQ * SEQ) / 256, blk, 0, stream>>>(mask, mbits);

    // 1. LN1 -> bf16
    ln_kernel<<<ROWS, blk, 0, stream>>>(x, alpha1, bias1, x2b);

    // 2. Fused QKV projection
    mfma_gemm<0, 0, 1, 128><<<dim3(24, 64), blk, 0, stream>>>(
        x2b, Wqkvt, bqkv, nullptr, qkv, ROWS, QKVSTR, FEAT);

    // 3. V transpose + flash attention
    transpose_v_kernel<<<BATCH * HEADS * (SEQ / 64), blk, 0, stream>>>(qkv + 2048, vtb);
    mfma_attn<<<BATCH * HEADS * (SEQ / AQ), blk, 0, stream>>>(qkv, vtb, mbits, attn_o);

    // 4. out = x + attn @ Wo + bo
    mfma_gemm<0, 1, 0, 128><<<dim3(8, 64), blk, 0, stream>>>(
        attn_o, Wot, bo, x, out, ROWS, FEAT, FEAT);

    // 5. LN2 -> bf16
    ln_kernel<<<ROWS, blk, 0, stream>>>(out, alpha2, bias2, x2b2);

    // 6. h = ELU(x2b2 @ W1 + b1)
    mfma_gemm<1, 0, 1, 64><<<dim3(FFP / 64, 64), blk, 0, stream>>>(
        x2b2, W1t, b1p, nullptr, hbuf, ROWS, FFP, FEAT);

    // 7. out += h @ W2 + b2
    mfma_gemm<0, 1, 0, 128><<<dim3(8, 64), blk, 0, stream>>>(
        hbuf, W2t, b2, out, out, ROWS, FEAT, FFP);
}

// Round 6
// 459.605 us; speedup vs baseline: 1.3306x; 1.0150x over previous
//
#include <hip/hip_runtime.h>
#include <hip/hip_bf16.h>
#include <math.h>

// Problem constants
#define BATCH 4
#define SEQ 2048
#define FEAT 1024
#define HEADS 16
#define HDIM 64
#define FF 500
#define FFP 512                 // FF padded to multiple of 128
#define ROWS (BATCH * SEQ)      // 8192
#define QKVSTR 3072             // fused q|k|v row stride
#define AQ 128                  // attn q-rows per block

typedef unsigned short ushortT;
typedef __attribute__((ext_vector_type(8))) short short8;   // 8 bf16 (4 VGPRs)
typedef __attribute__((ext_vector_type(4))) float floatx4;  // MFMA acc

#if defined(__has_builtin) && __has_builtin(__builtin_amdgcn_exp2f)
#define EXP2F(x) __builtin_amdgcn_exp2f(x)
#else
#define EXP2F(x) exp2f(x)
#endif

__device__ __forceinline__ unsigned short f2bf(float f) {
    unsigned int u = __builtin_bit_cast(unsigned int, f);
    u += 0x7fffu + ((u >> 16) & 1u);           // RNE
    return (unsigned short)(u >> 16);
}
__device__ __forceinline__ float bf2f(short b) {
    unsigned int u = ((unsigned int)(unsigned short)b) << 16;
    return __builtin_bit_cast(float, u);
}

__device__ __forceinline__ void async16(void* lds, const void* g) {
    __builtin_amdgcn_global_load_lds(
        (const __attribute__((address_space(1))) unsigned int*)g,
        (__attribute__((address_space(3))) unsigned int*)lds, 16, 0, 0);
}

// ---------------------------------------------------------------------------
// Unified prep: 6 weight transpose+convert tiles + bias concat/pad.
// Blocks 0..1023: Wq/Wk/Wv/Wo (256 tiles each); 1024..1151: W1; 1152..1279: W2;
// 1280: biases.
// ---------------------------------------------------------------------------
__global__ void prep_kernel(const float* __restrict__ Wq, const float* __restrict__ Wk,
                            const float* __restrict__ Wv, const float* __restrict__ Wo,
                            const float* __restrict__ W1, const float* __restrict__ W2,
                            const float* __restrict__ bq, const float* __restrict__ bk,
                            const float* __restrict__ bv, const float* __restrict__ b1,
                            ushortT* __restrict__ Wqkvt, ushortT* __restrict__ Wot,
                            ushortT* __restrict__ W1t, ushortT* __restrict__ W2t,
                            float* __restrict__ bqkv, float* __restrict__ b1p)
{
    const int t = blockIdx.x;
    const int tid = threadIdx.x;
    if (t == 1280) {
        for (int i = tid; i < QKVSTR; i += 256)
            bqkv[i] = (i < 1024) ? bq[i] : ((i < 2048) ? bk[i - 1024] : bv[i - 2048]);
        for (int i = tid; i < FFP; i += 256)
            b1p[i] = (i < FF) ? b1[i] : 0.0f;
        return;
    }
    const float* W; ushortT* Wt; int K, N, Kp, bx, by;
    if (t < 1024) {
        const int wi = t >> 8, lt = t & 255;
        bx = lt & 15; by = lt >> 4; K = FEAT; N = FEAT; Kp = FEAT;
        W  = (wi == 0) ? Wq : (wi == 1) ? Wk : (wi == 2) ? Wv : Wo;
        Wt = (wi == 3) ? Wot : (Wqkvt + (size_t)wi * FEAT * FEAT);
    } else if (t < 1152) {
        const int lt = t - 1024; bx = lt & 7; by = lt >> 3;
        K = FEAT; N = FF; Kp = FEAT; W = W1; Wt = W1t;
    } else {
        const int lt = t - 1152; bx = lt & 15; by = lt >> 4;
        K = FF; N = FEAT; Kp = FFP; W = W2; Wt = W2t;
    }

    __shared__ float T[64][65];
    const int n0 = bx * 64, k0 = by * 64;
    const int r = tid >> 4;            // 0..15
    const int c = (tid & 15) * 4;      // 0..60
    #pragma unroll
    for (int i = 0; i < 4; i++) {
        const int kk = k0 + r + i * 16;
        #pragma unroll
        for (int e = 0; e < 4; e++) {
            const int nn = n0 + c + e;
            T[r + i * 16][c + e] = (kk < K && nn < N) ? W[(size_t)kk * N + nn] : 0.0f;
        }
    }
    __syncthreads();
    #pragma unroll
    for (int i = 0; i < 4; i++) {
        const int nn = r + i * 16;
        ushort4 o;
        o.x = f2bf(T[c + 0][nn]);
        o.y = f2bf(T[c + 1][nn]);
        o.z = f2bf(T[c + 2][nn]);
        o.w = f2bf(T[c + 3][nn]);
        *(ushort4*)(Wt + (size_t)(n0 + nn) * Kp + k0 + c) = o;
    }
}
// note: W1t has 512 rows allocated; rows 500..511 get zeros (T[][]=0 there),
// which is exactly the padding we want.

// ---------------------------------------------------------------------------
// Mask bit-pack: int32 0/1 [B,S,S] -> bitmask dwords [B,S,S/32].
// ---------------------------------------------------------------------------
__global__ void maskbits_kernel(const int* __restrict__ mask,
                                unsigned int* __restrict__ bits)
{
    const size_t g = (size_t)blockIdx.x * 256 + threadIdx.x;
    const int lane = threadIdx.x & 63;
    const unsigned long long bal = __ballot(mask[g] != 0);
    if (lane == 0)  bits[g >> 5] = (unsigned int)bal;
    if (lane == 32) bits[g >> 5] = (unsigned int)(bal >> 32);
}

// ---------------------------------------------------------------------------
// LayerNorm -> bf16. One block per row; wave-shuffle reduction, 1 barrier.
// ---------------------------------------------------------------------------
__global__ void ln_kernel(const float* __restrict__ x,
                          const float* __restrict__ alpha,
                          const float* __restrict__ bias,
                          ushortT* __restrict__ out)
{
    __shared__ float p1[4], p2[4];
    const int row = blockIdx.x;
    const int tid = threadIdx.x;
    const int wave = tid >> 6, lane = tid & 63;
    float4 v = ((const float4*)(x + (size_t)row * FEAT))[tid];

    float s1 = v.x + v.y + v.z + v.w;
    float s2 = v.x * v.x + v.y * v.y + v.z * v.z + v.w * v.w;
    #pragma unroll
    for (int off = 32; off > 0; off >>= 1) {
        s1 += __shfl_xor(s1, off);
        s2 += __shfl_xor(s2, off);
    }
    if (lane == 0) { p1[wave] = s1; p2[wave] = s2; }
    __syncthreads();
    const float t1 = p1[0] + p1[1] + p1[2] + p1[3];
    const float t2 = p2[0] + p2[1] + p2[2] + p2[3];
    const float mean = t1 * (1.0f / 1024.0f);
    const float var = fmaxf(t2 - 1024.0f * mean * mean, 0.0f) * (1.0f / 1023.0f);
    const float inv = 1.0f / (sqrtf(var) + 1e-6f);

    const float4 a = ((const float4*)alpha)[tid];
    const float4 b = ((const float4*)bias)[tid];
    ushort4 o;
    o.x = f2bf(a.x * (v.x - mean) * inv + b.x);
    o.y = f2bf(a.y * (v.y - mean) * inv + b.y);
    o.z = f2bf(a.z * (v.z - mean) * inv + b.z);
    o.w = f2bf(a.w * (v.w - mean) * inv + b.w);
    ((ushort4*)(out + (size_t)row * FEAT))[tid] = o;
}

// ---------------------------------------------------------------------------
// bf16 MFMA GEMM, BK=64 as two 32-K planes (keeps 64B LDS rows: conflict-free).
// 128xBN tile (BN=128: 2x2 waves, 4x4 frags; BN=64: 4x1 waves, 2x4 frags).
// ---------------------------------------------------------------------------
template<int ACT, int RES, int OUT_BF16, int BN>
__global__ __launch_bounds__(256)
void mfma_gemm(const ushortT* __restrict__ A, const ushortT* __restrict__ Bt,
               const float* __restrict__ bias, const float* __restrict__ R,
               void* __restrict__ Cout, int M, int N, int K)
{
    constexpr int MT = (BN == 128) ? 4 : 2;
    constexpr int MSPAN = (BN == 128) ? 64 : 32;
    __shared__ ushortT As[2][128 * 32];
    __shared__ ushortT Bs[2][BN * 32];

    const int tid  = threadIdx.x;
    const int wave = tid >> 6, lane = tid & 63;
    const int quad = lane >> 4, l16 = lane & 15;
    const int wm = (BN == 128) ? (wave >> 1) : wave;
    const int wn = (BN == 128) ? (wave & 1) : 0;
    const int row0 = blockIdx.y * 128, col0 = blockIdx.x * BN;

    const floatx4 z4 = {0.f, 0.f, 0.f, 0.f};
    floatx4 acc[MT][4];
    #pragma unroll
    for (int i = 0; i < MT; i++)
        #pragma unroll
        for (int j = 0; j < 4; j++) acc[i][j] = z4;

    for (int k0 = 0; k0 < K; k0 += 64) {
        __syncthreads();
        #pragma unroll
        for (int kh = 0; kh < 2; kh++) {
            #pragma unroll
            for (int i = 0; i < 2; i++) {
                const int rbase = 16 * (wave + 4 * i);
                const int r = rbase + (lane >> 2);
                const int co = (lane & 3) * 8;
                async16((char*)As[kh] + rbase * 64,
                        A + (size_t)(row0 + r) * K + k0 + kh * 32 + co);
            }
            if (BN == 128) {
                #pragma unroll
                for (int i = 0; i < 2; i++) {
                    const int rbase = 16 * (wave + 4 * i);
                    const int r = rbase + (lane >> 2);
                    const int co = (lane & 3) * 8;
                    async16((char*)Bs[kh] + rbase * 64,
                            Bt + (size_t)(col0 + r) * K + k0 + kh * 32 + co);
                }
            } else {
                const int rbase = 16 * wave;
                const int r = rbase + (lane >> 2);
                const int co = (lane & 3) * 8;
                async16((char*)Bs[kh] + rbase * 64,
                        Bt + (size_t)(col0 + r) * K + k0 + kh * 32 + co);
            }
        }
        __syncthreads();

        #pragma unroll
        for (int kh = 0; kh < 2; kh++) {
            short8 af[MT], bf[4];
            #pragma unroll
            for (int mt = 0; mt < MT; mt++)
                af[mt] = *(const short8*)&As[kh][(MSPAN * wm + 16 * mt + l16) * 32 + quad * 8];
            #pragma unroll
            for (int nt = 0; nt < 4; nt++)
                bf[nt] = *(const short8*)&Bs[kh][(64 * wn + 16 * nt + l16) * 32 + quad * 8];
            #pragma unroll
            for (int mt = 0; mt < MT; mt++)
                #pragma unroll
                for (int nt = 0; nt < 4; nt++)
                    acc[mt][nt] = __builtin_amdgcn_mfma_f32_16x16x32_bf16(
                        af[mt], bf[nt], acc[mt][nt], 0, 0, 0);
        }
    }

    #pragma unroll
    for (int mt = 0; mt < MT; mt++) {
        #pragma unroll
        for (int nt = 0; nt < 4; nt++) {
            const int col = col0 + 64 * wn + 16 * nt + l16;
            #pragma unroll
            for (int r = 0; r < 4; r++) {
                const int row = row0 + MSPAN * wm + 16 * mt + quad * 4 + r;
                float val = acc[mt][nt][r] + bias[col];
                if (ACT == 1) val = (val > 0.0f) ? val : (__expf(val) - 1.0f);
                if (RES) val += R[(size_t)row * N + col];
                if (OUT_BF16)
                    ((ushortT*)Cout)[(size_t)row * N + col] = f2bf(val);
                else
                    ((float*)Cout)[(size_t)row * N + col] = val;
            }
        }
    }
}

// ---------------------------------------------------------------------------
// V transpose: v bf16 (rows stride QKVSTR) -> vt bf16 [B][H][64 d][SEQ j]
// ---------------------------------------------------------------------------
__global__ void transpose_v_kernel(const ushortT* __restrict__ v, ushortT* __restrict__ vt)
{
    __shared__ ushortT T[64][80];
    const int bid = blockIdx.x;
    const int jt = bid & 31, h = (bid >> 5) & 15, b = bid >> 9;
    const int j0 = jt * 64;
    const int tid = threadIdx.x;

    const int j = tid >> 2;
    #pragma unroll
    for (int i = 0; i < 2; i++) {
        const int c = (tid & 3) * 2 + i;
        short8 val = *(const short8*)(v + (size_t)(b * SEQ + j0 + j) * QKVSTR + h * 64 + c * 8);
        *(short8*)&T[j][c * 8] = val;
    }
    __syncthreads();
    const int d = tid >> 2;
    #pragma unroll
    for (int i = 0; i < 2; i++) {
        const int cj = (tid & 3) * 2 + i;
        union { short8 v8; ushortT u[8]; } tmp;
        #pragma unroll
        for (int e = 0; e < 8; e++) tmp.u[e] = T[cj * 8 + e][d];
        *(short8*)(vt + ((size_t)((b * HEADS + h) * 64 + d)) * SEQ + j0 + cj * 8) = tmp.v8;
    }
}

// ---------------------------------------------------------------------------
// MFMA flash attention, 8-wave repartition. Same algorithm/numerics as the
// proven 4-wave version (125.5us): S^T form, no-max softmax, Ps-LDS P path,
// dbuf K/V, XCD swizzle (FETCH 140->27MB), setprio, mask prefetch. Round-5
// counters showed latency-bound (VALU 57%, Mfma 26%, occ ~20%): per-wave
// serial chain too long, too few waves. Fix: 512 threads, 8 waves x 16 q-rows
// (was 4 x 32): per-wave tile work halves (18 MFMA, 16 exp), per-wave VGPR
// drops, wave count per CU rises -> latency hiding. Total work unchanged.
// ---------------------------------------------------------------------------
__global__ __launch_bounds__(512)
void mfma_attn(const ushortT* __restrict__ qkv, const ushortT* __restrict__ vt,
               const unsigned int* __restrict__ mbits, ushortT* __restrict__ attn_out)
{
    __shared__ ushortT Ks[2][64 * 64];    // [j][d] swizzled
    __shared__ ushortT Vts[2][64 * 64];   // [d][j] swizzled
    __shared__ ushortT Ps[AQ * 64];       // [m][j] swizzled, wave-private rows

    const int tid = threadIdx.x;
    const int wave = tid >> 6, lane = tid & 63;   // wave 0..7
    const int quad = lane >> 4, l16 = lane & 15;
    // XCD-aware bijective swizzle (grid=1024, 1024%8==0): hw%8 = XCD.
    const int bid = ((blockIdx.x & 7) << 7) | (blockIdx.x >> 3);
    const int qt = bid & 15, h = (bid >> 4) & 15, b = bid >> 8;
    const int q0 = qt * AQ;

    const ushortT* qptr = qkv;
    const ushortT* kptr = qkv + 1024;

    // Q fragment: this wave owns rows q0 + 16*wave .. +15. Pre-scaled.
    short8 qf[2];
    {
        const size_t qrow = (size_t)(b * SEQ + q0 + 16 * wave + l16);
        short8 t0 = *(const short8*)(qptr + qrow * QKVSTR + h * 64 + quad * 8);
        short8 t1 = *(const short8*)(qptr + qrow * QKVSTR + h * 64 + 32 + quad * 8);
        const float cs = 0.125f * 1.4426950408889634f;
        #pragma unroll
        for (int i = 0; i < 8; i++) {
            qf[0][i] = (short)f2bf(bf2f(t0[i]) * cs);
            qf[1][i] = (short)f2bf(bf2f(t1[i]) * cs);
        }
    }

    short8 ones8;
    #pragma unroll
    for (int i = 0; i < 8; i++) ones8[i] = (short)0x3F80;  // bf16 1.0

    const floatx4 z4 = {0.f, 0.f, 0.f, 0.f};
    floatx4 o[4];
    #pragma unroll
    for (int dt = 0; dt < 4; dt++) o[dt] = z4;
    floatx4 lacc = z4;

    // staging: 512 threads, one K short8 + one V short8 each.
    const int rr = tid >> 3;            // 0..63 (row of K tile / d-row of V tile)
    const int c0 = tid & 7;             // 0..7 (16B chunk within row)
    const ushortT* gk = kptr + (size_t)(b * SEQ + rr) * QKVSTR + h * 64 + c0 * 8;
    const ushortT* gv = vt + ((size_t)((b * HEADS + h) * 64 + rr)) * SEQ + c0 * 8;
    short8 rk, rv;

#define ATTN_ISSUE() {                                                       \
    rk = *(const short8*)gk;                                                 \
    rv = *(const short8*)gv;                                                 \
    gk += (size_t)64 * QKVSTR; gv += 64; }

#define ATTN_WRITE(BI) {                                                     \
    *(short8*)&Ks[BI][rr * 64 + ((c0 ^ (rr & 7)) * 8)] = rk;                 \
    *(short8*)&Vts[BI][rr * 64 + ((c0 ^ (rr & 7)) * 8)] = rv; }

    const unsigned int* mrowp =
        mbits + (size_t)(b * SEQ + q0 + 16 * wave + l16) * (SEQ / 32);
    const int mloc = 16 * wave + l16;

    // Prologue: stage tile 0; preload mask words for tile 0.
    ATTN_ISSUE();
    ATTN_WRITE(0);
    unsigned int w0 = mrowp[0], w1 = mrowp[1];

    #pragma unroll 2
    for (int jt = 0; jt < 32; jt++) {
        __syncthreads();
        const int cur = jt & 1;
        unsigned int wn0, wn1;
        if (jt < 31) {
            ATTN_ISSUE();
            wn0 = mrowp[jt * 2 + 2];
            wn1 = mrowp[jt * 2 + 3];
        }

        // S^T = K @ Q^T
        floatx4 st[4];
        __builtin_amdgcn_s_setprio(1);
        #pragma unroll
        for (int nt = 0; nt < 4; nt++) {
            const int j = nt * 16 + l16;
            short8 ka0 = *(const short8*)&Ks[cur][j * 64 + ((quad ^ (j & 7)) * 8)];
            short8 ka1 = *(const short8*)&Ks[cur][j * 64 + (((4 + quad) ^ (j & 7)) * 8)];
            floatx4 t = z4;
            t = __builtin_amdgcn_mfma_f32_16x16x32_bf16(ka0, qf[0], t, 0, 0, 0);
            t = __builtin_amdgcn_mfma_f32_16x16x32_bf16(ka1, qf[1], t, 0, 0, 0);
            st[nt] = t;
        }
        __builtin_amdgcn_s_setprio(0);

        // softmax: p = exp2(masked ? 0 : s); packed bf16 writes into Ps[m][j]
        #pragma unroll
        for (int nt = 0; nt < 4; nt++) {
            const unsigned int ww = (nt & 2) ? w1 : w0;
            const unsigned int wsh = ww >> ((nt & 1) * 16 + quad * 4);
            float p[4];
            p[0] = EXP2F((wsh & 1u) ? st[nt][0] : 0.0f);
            p[1] = EXP2F((wsh & 2u) ? st[nt][1] : 0.0f);
            p[2] = EXP2F((wsh & 4u) ? st[nt][2] : 0.0f);
            p[3] = EXP2F((wsh & 8u) ? st[nt][3] : 0.0f);
            const int j0 = nt * 16 + quad * 4;
            const int chunk = (j0 >> 3) ^ (mloc & 7);
            const int ci = j0 & 7;
            ushortT* dst = &Ps[mloc * 64 + chunk * 8 + ci];
            *(__hip_bfloat162*)(dst)     = __float22bfloat162_rn(make_float2(p[0], p[1]));
            *(__hip_bfloat162*)(dst + 2) = __float22bfloat162_rn(make_float2(p[2], p[3]));
        }

        // O += P @ V ; lacc += P @ ones  (Ps rows wave-private: no barrier)
        short8 pa0 = *(const short8*)&Ps[mloc * 64 + ((quad ^ (mloc & 7)) * 8)];
        short8 pa1 = *(const short8*)&Ps[mloc * 64 + (((4 + quad) ^ (mloc & 7)) * 8)];
        lacc = __builtin_amdgcn_mfma_f32_16x16x32_bf16(pa0, ones8, lacc, 0, 0, 0);
        lacc = __builtin_amdgcn_mfma_f32_16x16x32_bf16(pa1, ones8, lacc, 0, 0, 0);
        __builtin_amdgcn_s_setprio(1);
        #pragma unroll
        for (int dt = 0; dt < 4; dt++) {
            const int d = dt * 16 + l16;
            short8 vb0 = *(const short8*)&Vts[cur][d * 64 + ((quad ^ (d & 7)) * 8)];
            short8 vb1 = *(const short8*)&Vts[cur][d * 64 + (((4 + quad) ^ (d & 7)) * 8)];
            o[dt] = __builtin_amdgcn_mfma_f32_16x16x32_bf16(pa0, vb0, o[dt], 0, 0, 0);
            o[dt] = __builtin_amdgcn_mfma_f32_16x16x32_bf16(pa1, vb1, o[dt], 0, 0, 0);
        }
        __builtin_amdgcn_s_setprio(0);

        if (jt < 31) {
            ATTN_WRITE(cur ^ 1);
            w0 = wn0; w1 = wn1;
        }
    }

    // Normalize + store bf16.
    #pragma unroll
    for (int r = 0; r < 4; r++) {
        const float inv_l = 1.0f / lacc[r];
        const size_t row = (size_t)(b * SEQ + q0 + 16 * wave + quad * 4 + r);
        #pragma unroll
        for (int dt = 0; dt < 4; dt++) {
            attn_out[row * FEAT + h * 64 + dt * 16 + l16] = f2bf(o[dt][r] * inv_l);
        }
    }
#undef ATTN_ISSUE
#undef ATTN_WRITE
}

// ---------------------------------------------------------------------------
// Launch
// ---------------------------------------------------------------------------
extern "C" void kernel_launch(void* const* d_in, const int* in_sizes, int n_in,
                              void* d_out, int out_size, void* d_ws, size_t ws_size,
                              hipStream_t stream)
{
    const float* x      = (const float*)d_in[0];
    const int*   mask   = (const int*)d_in[1];
    const float* alpha1 = (const float*)d_in[2];
    const float* bias1  = (const float*)d_in[3];
    const float* alpha2 = (const float*)d_in[4];
    const float* bias2  = (const float*)d_in[5];
    const float* Wq     = (const float*)d_in[6];
    const float* bq     = (const float*)d_in[7];
    const float* Wk     = (const float*)d_in[8];
    const float* bk     = (const float*)d_in[9];
    const float* Wv     = (const float*)d_in[10];
    const float* bv     = (const float*)d_in[11];
    const float* Wo     = (const float*)d_in[12];
    const float* bo     = (const float*)d_in[13];
    const float* W1     = (const float*)d_in[14];
    const float* b1     = (const float*)d_in[15];
    const float* W2     = (const float*)d_in[16];
    const float* b2     = (const float*)d_in[17];
    float* out = (float*)d_out;

    char* ws = (char*)d_ws;
    const size_t MB = 1024 * 1024;
    ushortT* x2b    = (ushortT*)(ws);              // LN1 out; attn out later
    ushortT* attn_o = (ushortT*)(ws);
    ushortT* qkv    = (ushortT*)(ws + 16 * MB);    // fused q|k|v
    ushortT* x2b2   = (ushortT*)(ws + 16 * MB);    // LN2 out (after attn)
    ushortT* hbuf   = (ushortT*)(ws + 32 * MB);    // FF hidden
    ushortT* vtb    = (ushortT*)(ws + 64 * MB);
    ushortT* Wqkvt  = (ushortT*)(ws + 80 * MB);    // 6 MB  [3072][1024]
    ushortT* Wot    = (ushortT*)(ws + 86 * MB);    // 2 MB
    ushortT* W1t    = (ushortT*)(ws + 88 * MB);    // 1 MB  [512][1024]
    ushortT* W2t    = (ushortT*)(ws + 89 * MB);    // 1 MB  [1024][512]
    float*   b1p    = (float*)  (ws + 90 * MB);
    float*   bqkv   = (float*)  (ws + 90 * MB + 16384);
    unsigned int* mbits = (unsigned int*)(ws + 91 * MB); // 2 MB

    const dim3 blk(256);

    // Prep (1 launch) + mask pack
    prep_kernel<<<1281, blk, 0, stream>>>(Wq, Wk, Wv, Wo, W1, W2, bq, bk, bv, b1,
                                          Wqkvt, Wot, W1t, W2t, bqkv, b1p);
    maskbits_kernel<<<(BATCH * SEQ * SEQ) / 256, blk, 0, stream>>>(mask, mbits);

    // 1. LN1 -> bf16
    ln_kernel<<<ROWS, blk, 0, stream>>>(x, alpha1, bias1, x2b);

    // 2. Fused QKV projection
    mfma_gemm<0, 0, 1, 128><<<dim3(24, 64), blk, 0, stream>>>(
        x2b, Wqkvt, bqkv, nullptr, qkv, ROWS, QKVSTR, FEAT);

    // 3. V transpose + flash attention (512-thread blocks)
    transpose_v_kernel<<<BATCH * HEADS * (SEQ / 64), blk, 0, stream>>>(qkv + 2048, vtb);
    mfma_attn<<<BATCH * HEADS * (SEQ / AQ), dim3(512), 0, stream>>>(qkv, vtb, mbits, attn_o);

    // 4. out = x + attn @ Wo + bo
    mfma_gemm<0, 1, 0, 128><<<dim3(8, 64), blk, 0, stream>>>(
        attn_o, Wot, bo, x, out, ROWS, FEAT, FEAT);

    // 5. LN2 -> bf16
    ln_kernel<<<ROWS, blk, 0, stream>>>(out, alpha2, bias2, x2b2);

    // 6. h = ELU(x2b2 @ W1 + b1)
    mfma_gemm<1, 0, 1, 64><<<dim3(FFP / 64, 64), blk, 0, stream>>>(
        x2b2, W1t, b1p, nullptr, hbuf, ROWS, FFP, FEAT);

    // 7. out += h @ W2 + b2
    mfma_gemm<0, 1, 0, 128><<<dim3(8, 64), blk, 0, stream>>>(
        hbuf, W2t, b2, out, out, ROWS, FEAT, FFP);
}

// Round 7
// 459.460 us; speedup vs baseline: 1.3310x; 1.0003x over previous
//
#include <hip/hip_runtime.h>
#include <hip/hip_bf16.h>
#include <math.h>

// Problem constants
#define BATCH 4
#define SEQ 2048
#define FEAT 1024
#define HEADS 16
#define HDIM 64
#define FF 500
#define FFP 512                 // FF padded to multiple of 128
#define ROWS (BATCH * SEQ)      // 8192
#define QKVSTR 3072             // fused q|k|v row stride
#define AQ 128                  // attn q-rows per block

typedef unsigned short ushortT;
typedef __attribute__((ext_vector_type(8))) short short8;   // 8 bf16 (4 VGPRs)
typedef __attribute__((ext_vector_type(4))) float floatx4;  // MFMA acc

#if defined(__has_builtin) && __has_builtin(__builtin_amdgcn_exp2f)
#define EXP2F(x) __builtin_amdgcn_exp2f(x)
#else
#define EXP2F(x) exp2f(x)
#endif

__device__ __forceinline__ unsigned short f2bf(float f) {
    unsigned int u = __builtin_bit_cast(unsigned int, f);
    u += 0x7fffu + ((u >> 16) & 1u);           // RNE
    return (unsigned short)(u >> 16);
}
__device__ __forceinline__ float bf2f(short b) {
    unsigned int u = ((unsigned int)(unsigned short)b) << 16;
    return __builtin_bit_cast(float, u);
}

__device__ __forceinline__ void async16(void* lds, const void* g) {
    __builtin_amdgcn_global_load_lds(
        (const __attribute__((address_space(1))) unsigned int*)g,
        (__attribute__((address_space(3))) unsigned int*)lds, 16, 0, 0);
}

// ---------------------------------------------------------------------------
// Unified prep: 6 weight transpose+convert tiles + bias concat/pad.
// Blocks 0..1023: Wq/Wk/Wv/Wo (256 tiles each); 1024..1151: W1; 1152..1279: W2;
// 1280: biases.
// ---------------------------------------------------------------------------
__global__ void prep_kernel(const float* __restrict__ Wq, const float* __restrict__ Wk,
                            const float* __restrict__ Wv, const float* __restrict__ Wo,
                            const float* __restrict__ W1, const float* __restrict__ W2,
                            const float* __restrict__ bq, const float* __restrict__ bk,
                            const float* __restrict__ bv, const float* __restrict__ b1,
                            ushortT* __restrict__ Wqkvt, ushortT* __restrict__ Wot,
                            ushortT* __restrict__ W1t, ushortT* __restrict__ W2t,
                            float* __restrict__ bqkv, float* __restrict__ b1p)
{
    const int t = blockIdx.x;
    const int tid = threadIdx.x;
    if (t == 1280) {
        for (int i = tid; i < QKVSTR; i += 256)
            bqkv[i] = (i < 1024) ? bq[i] : ((i < 2048) ? bk[i - 1024] : bv[i - 2048]);
        for (int i = tid; i < FFP; i += 256)
            b1p[i] = (i < FF) ? b1[i] : 0.0f;
        return;
    }
    const float* W; ushortT* Wt; int K, N, Kp, bx, by;
    if (t < 1024) {
        const int wi = t >> 8, lt = t & 255;
        bx = lt & 15; by = lt >> 4; K = FEAT; N = FEAT; Kp = FEAT;
        W  = (wi == 0) ? Wq : (wi == 1) ? Wk : (wi == 2) ? Wv : Wo;
        Wt = (wi == 3) ? Wot : (Wqkvt + (size_t)wi * FEAT * FEAT);
    } else if (t < 1152) {
        const int lt = t - 1024; bx = lt & 7; by = lt >> 3;
        K = FEAT; N = FF; Kp = FEAT; W = W1; Wt = W1t;
    } else {
        const int lt = t - 1152; bx = lt & 15; by = lt >> 4;
        K = FF; N = FEAT; Kp = FFP; W = W2; Wt = W2t;
    }

    __shared__ float T[64][65];
    const int n0 = bx * 64, k0 = by * 64;
    const int r = tid >> 4;            // 0..15
    const int c = (tid & 15) * 4;      // 0..60
    #pragma unroll
    for (int i = 0; i < 4; i++) {
        const int kk = k0 + r + i * 16;
        #pragma unroll
        for (int e = 0; e < 4; e++) {
            const int nn = n0 + c + e;
            T[r + i * 16][c + e] = (kk < K && nn < N) ? W[(size_t)kk * N + nn] : 0.0f;
        }
    }
    __syncthreads();
    #pragma unroll
    for (int i = 0; i < 4; i++) {
        const int nn = r + i * 16;
        ushort4 o;
        o.x = f2bf(T[c + 0][nn]);
        o.y = f2bf(T[c + 1][nn]);
        o.z = f2bf(T[c + 2][nn]);
        o.w = f2bf(T[c + 3][nn]);
        *(ushort4*)(Wt + (size_t)(n0 + nn) * Kp + k0 + c) = o;
    }
}
// note: W1t has 512 rows allocated; rows 500..511 get zeros (T[][]=0 there),
// which is exactly the padding we want.

// ---------------------------------------------------------------------------
// Mask bit-pack: int32 0/1 [B,S,S] -> bitmask dwords [B,S,S/32].
// ---------------------------------------------------------------------------
__global__ void maskbits_kernel(const int* __restrict__ mask,
                                unsigned int* __restrict__ bits)
{
    const size_t g = (size_t)blockIdx.x * 256 + threadIdx.x;
    const int lane = threadIdx.x & 63;
    const unsigned long long bal = __ballot(mask[g] != 0);
    if (lane == 0)  bits[g >> 5] = (unsigned int)bal;
    if (lane == 32) bits[g >> 5] = (unsigned int)(bal >> 32);
}

// ---------------------------------------------------------------------------
// LayerNorm -> bf16. One block per row; wave-shuffle reduction, 1 barrier.
// ---------------------------------------------------------------------------
__global__ void ln_kernel(const float* __restrict__ x,
                          const float* __restrict__ alpha,
                          const float* __restrict__ bias,
                          ushortT* __restrict__ out)
{
    __shared__ float p1[4], p2[4];
    const int row = blockIdx.x;
    const int tid = threadIdx.x;
    const int wave = tid >> 6, lane = tid & 63;
    float4 v = ((const float4*)(x + (size_t)row * FEAT))[tid];

    float s1 = v.x + v.y + v.z + v.w;
    float s2 = v.x * v.x + v.y * v.y + v.z * v.z + v.w * v.w;
    #pragma unroll
    for (int off = 32; off > 0; off >>= 1) {
        s1 += __shfl_xor(s1, off);
        s2 += __shfl_xor(s2, off);
    }
    if (lane == 0) { p1[wave] = s1; p2[wave] = s2; }
    __syncthreads();
    const float t1 = p1[0] + p1[1] + p1[2] + p1[3];
    const float t2 = p2[0] + p2[1] + p2[2] + p2[3];
    const float mean = t1 * (1.0f / 1024.0f);
    const float var = fmaxf(t2 - 1024.0f * mean * mean, 0.0f) * (1.0f / 1023.0f);
    const float inv = 1.0f / (sqrtf(var) + 1e-6f);

    const float4 a = ((const float4*)alpha)[tid];
    const float4 b = ((const float4*)bias)[tid];
    ushort4 o;
    o.x = f2bf(a.x * (v.x - mean) * inv + b.x);
    o.y = f2bf(a.y * (v.y - mean) * inv + b.y);
    o.z = f2bf(a.z * (v.z - mean) * inv + b.z);
    o.w = f2bf(a.w * (v.w - mean) * inv + b.w);
    ((ushort4*)(out + (size_t)row * FEAT))[tid] = o;
}

// ---------------------------------------------------------------------------
// bf16 MFMA GEMM, BK=64 as two 32-K planes (keeps 64B LDS rows: conflict-free).
// 128xBN tile (BN=128: 2x2 waves, 4x4 frags; BN=64: 4x1 waves, 2x4 frags).
// XCD-chunked block swizzle (T1): each XCD gets a contiguous run of x-major
// block ids -> A row-panels reused within one XCD's L2. All grids %8 == 0.
// ---------------------------------------------------------------------------
template<int ACT, int RES, int OUT_BF16, int BN>
__global__ __launch_bounds__(256)
void mfma_gemm(const ushortT* __restrict__ A, const ushortT* __restrict__ Bt,
               const float* __restrict__ bias, const float* __restrict__ R,
               void* __restrict__ Cout, int M, int N, int K)
{
    constexpr int MT = (BN == 128) ? 4 : 2;
    constexpr int MSPAN = (BN == 128) ? 64 : 32;
    __shared__ ushortT As[2][128 * 32];
    __shared__ ushortT Bs[2][BN * 32];

    const int tid  = threadIdx.x;
    const int wave = tid >> 6, lane = tid & 63;
    const int quad = lane >> 4, l16 = lane & 15;
    const int wm = (BN == 128) ? (wave >> 1) : wave;
    const int wn = (BN == 128) ? (wave & 1) : 0;

    const int nbx = gridDim.x;
    int lid = blockIdx.y * nbx + blockIdx.x;
    const int cpx = (nbx * gridDim.y) >> 3;     // grid %8 == 0 for all launches
    lid = (lid & 7) * cpx + (lid >> 3);
    const int row0 = (lid / nbx) * 128, col0 = (lid % nbx) * BN;

    const floatx4 z4 = {0.f, 0.f, 0.f, 0.f};
    floatx4 acc[MT][4];
    #pragma unroll
    for (int i = 0; i < MT; i++)
        #pragma unroll
        for (int j = 0; j < 4; j++) acc[i][j] = z4;

    for (int k0 = 0; k0 < K; k0 += 64) {
        __syncthreads();
        #pragma unroll
        for (int kh = 0; kh < 2; kh++) {
            #pragma unroll
            for (int i = 0; i < 2; i++) {
                const int rbase = 16 * (wave + 4 * i);
                const int r = rbase + (lane >> 2);
                const int co = (lane & 3) * 8;
                async16((char*)As[kh] + rbase * 64,
                        A + (size_t)(row0 + r) * K + k0 + kh * 32 + co);
            }
            if (BN == 128) {
                #pragma unroll
                for (int i = 0; i < 2; i++) {
                    const int rbase = 16 * (wave + 4 * i);
                    const int r = rbase + (lane >> 2);
                    const int co = (lane & 3) * 8;
                    async16((char*)Bs[kh] + rbase * 64,
                            Bt + (size_t)(col0 + r) * K + k0 + kh * 32 + co);
                }
            } else {
                const int rbase = 16 * wave;
                const int r = rbase + (lane >> 2);
                const int co = (lane & 3) * 8;
                async16((char*)Bs[kh] + rbase * 64,
                        Bt + (size_t)(col0 + r) * K + k0 + kh * 32 + co);
            }
        }
        __syncthreads();

        #pragma unroll
        for (int kh = 0; kh < 2; kh++) {
            short8 af[MT], bf[4];
            #pragma unroll
            for (int mt = 0; mt < MT; mt++)
                af[mt] = *(const short8*)&As[kh][(MSPAN * wm + 16 * mt + l16) * 32 + quad * 8];
            #pragma unroll
            for (int nt = 0; nt < 4; nt++)
                bf[nt] = *(const short8*)&Bs[kh][(64 * wn + 16 * nt + l16) * 32 + quad * 8];
            #pragma unroll
            for (int mt = 0; mt < MT; mt++)
                #pragma unroll
                for (int nt = 0; nt < 4; nt++)
                    acc[mt][nt] = __builtin_amdgcn_mfma_f32_16x16x32_bf16(
                        af[mt], bf[nt], acc[mt][nt], 0, 0, 0);
        }
    }

    #pragma unroll
    for (int mt = 0; mt < MT; mt++) {
        #pragma unroll
        for (int nt = 0; nt < 4; nt++) {
            const int col = col0 + 64 * wn + 16 * nt + l16;
            #pragma unroll
            for (int r = 0; r < 4; r++) {
                const int row = row0 + MSPAN * wm + 16 * mt + quad * 4 + r;
                float val = acc[mt][nt][r] + bias[col];
                if (ACT == 1) val = (val > 0.0f) ? val : (__expf(val) - 1.0f);
                if (RES) val += R[(size_t)row * N + col];
                if (OUT_BF16)
                    ((ushortT*)Cout)[(size_t)row * N + col] = f2bf(val);
                else
                    ((float*)Cout)[(size_t)row * N + col] = val;
            }
        }
    }
}

// ---------------------------------------------------------------------------
// V transpose: v bf16 (rows stride QKVSTR) -> vt bf16 [B][H][64 d][SEQ j]
// ---------------------------------------------------------------------------
__global__ void transpose_v_kernel(const ushortT* __restrict__ v, ushortT* __restrict__ vt)
{
    __shared__ ushortT T[64][80];
    const int bid = blockIdx.x;
    const int jt = bid & 31, h = (bid >> 5) & 15, b = bid >> 9;
    const int j0 = jt * 64;
    const int tid = threadIdx.x;

    const int j = tid >> 2;
    #pragma unroll
    for (int i = 0; i < 2; i++) {
        const int c = (tid & 3) * 2 + i;
        short8 val = *(const short8*)(v + (size_t)(b * SEQ + j0 + j) * QKVSTR + h * 64 + c * 8);
        *(short8*)&T[j][c * 8] = val;
    }
    __syncthreads();
    const int d = tid >> 2;
    #pragma unroll
    for (int i = 0; i < 2; i++) {
        const int cj = (tid & 3) * 2 + i;
        union { short8 v8; ushortT u[8]; } tmp;
        #pragma unroll
        for (int e = 0; e < 8; e++) tmp.u[e] = T[cj * 8 + e][d];
        *(short8*)(vt + ((size_t)((b * HEADS + h) * 64 + d)) * SEQ + j0 + cj * 8) = tmp.v8;
    }
}

// ---------------------------------------------------------------------------
// MFMA flash attention, 8-wave x 16 q-rows. S^T form, no-max softmax, Ps-LDS
// P path, XCD swizzle, setprio, mask prefetch. Round-6 (dbuf K/V, 48KB LDS,
// 106.8us) left a residency gap: 3 blocks/CU resident vs grid 4/CU -> partial
// occupancy + a 1-block/CU tail. Round 7: SINGLE-buffer K/V (staging already
// register-held across the compute phase, so dbuf was redundant) -> 32KB LDS
// -> all 4 blocks/CU resident, no tail. Cost: 2 barriers/tile instead of 1.
// ---------------------------------------------------------------------------
__global__ __launch_bounds__(512)
void mfma_attn(const ushortT* __restrict__ qkv, const ushortT* __restrict__ vt,
               const unsigned int* __restrict__ mbits, ushortT* __restrict__ attn_out)
{
    __shared__ ushortT Ks[64 * 64];    // [j][d] swizzled (single buffer)
    __shared__ ushortT Vts[64 * 64];   // [d][j] swizzled (single buffer)
    __shared__ ushortT Ps[AQ * 64];    // [m][j] swizzled, wave-private rows

    const int tid = threadIdx.x;
    const int wave = tid >> 6, lane = tid & 63;   // wave 0..7
    const int quad = lane >> 4, l16 = lane & 15;
    // XCD-aware bijective swizzle (grid=1024, 1024%8==0): hw%8 = XCD.
    const int bid = ((blockIdx.x & 7) << 7) | (blockIdx.x >> 3);
    const int qt = bid & 15, h = (bid >> 4) & 15, b = bid >> 8;
    const int q0 = qt * AQ;

    const ushortT* qptr = qkv;
    const ushortT* kptr = qkv + 1024;

    // Q fragment: this wave owns rows q0 + 16*wave .. +15. Pre-scaled.
    short8 qf[2];
    {
        const size_t qrow = (size_t)(b * SEQ + q0 + 16 * wave + l16);
        short8 t0 = *(const short8*)(qptr + qrow * QKVSTR + h * 64 + quad * 8);
        short8 t1 = *(const short8*)(qptr + qrow * QKVSTR + h * 64 + 32 + quad * 8);
        const float cs = 0.125f * 1.4426950408889634f;
        #pragma unroll
        for (int i = 0; i < 8; i++) {
            qf[0][i] = (short)f2bf(bf2f(t0[i]) * cs);
            qf[1][i] = (short)f2bf(bf2f(t1[i]) * cs);
        }
    }

    short8 ones8;
    #pragma unroll
    for (int i = 0; i < 8; i++) ones8[i] = (short)0x3F80;  // bf16 1.0

    const floatx4 z4 = {0.f, 0.f, 0.f, 0.f};
    floatx4 o[4];
    #pragma unroll
    for (int dt = 0; dt < 4; dt++) o[dt] = z4;
    floatx4 lacc = z4;

    // staging: 512 threads, one K short8 + one V short8 each.
    const int rr = tid >> 3;            // 0..63 (row of K tile / d-row of V tile)
    const int c0 = tid & 7;             // 0..7 (16B chunk within row)
    const ushortT* gk = kptr + (size_t)(b * SEQ + rr) * QKVSTR + h * 64 + c0 * 8;
    const ushortT* gv = vt + ((size_t)((b * HEADS + h) * 64 + rr)) * SEQ + c0 * 8;
    short8 rk, rv;

#define ATTN_ISSUE() {                                                       \
    rk = *(const short8*)gk;                                                 \
    rv = *(const short8*)gv;                                                 \
    gk += (size_t)64 * QKVSTR; gv += 64; }

#define ATTN_WRITE() {                                                       \
    *(short8*)&Ks[rr * 64 + ((c0 ^ (rr & 7)) * 8)] = rk;                     \
    *(short8*)&Vts[rr * 64 + ((c0 ^ (rr & 7)) * 8)] = rv; }

    const unsigned int* mrowp =
        mbits + (size_t)(b * SEQ + q0 + 16 * wave + l16) * (SEQ / 32);
    const int mloc = 16 * wave + l16;

    // Prologue: load tile 0 into regs; preload mask words for tile 0.
    ATTN_ISSUE();
    unsigned int w0 = mrowp[0], w1 = mrowp[1];

    #pragma unroll 2
    for (int jt = 0; jt < 32; jt++) {
        __syncthreads();               // A: all waves done reading prev tile
        ATTN_WRITE();                  // regs (tile jt) -> LDS
        __syncthreads();               // B: LDS tile jt visible to all
        unsigned int wn0 = 0, wn1 = 0;
        if (jt < 31) {
            ATTN_ISSUE();              // tile jt+1 -> regs; covered by compute
            wn0 = mrowp[jt * 2 + 2];
            wn1 = mrowp[jt * 2 + 3];
        }

        // S^T = K @ Q^T
        floatx4 st[4];
        __builtin_amdgcn_s_setprio(1);
        #pragma unroll
        for (int nt = 0; nt < 4; nt++) {
            const int j = nt * 16 + l16;
            short8 ka0 = *(const short8*)&Ks[j * 64 + ((quad ^ (j & 7)) * 8)];
            short8 ka1 = *(const short8*)&Ks[j * 64 + (((4 + quad) ^ (j & 7)) * 8)];
            floatx4 t = z4;
            t = __builtin_amdgcn_mfma_f32_16x16x32_bf16(ka0, qf[0], t, 0, 0, 0);
            t = __builtin_amdgcn_mfma_f32_16x16x32_bf16(ka1, qf[1], t, 0, 0, 0);
            st[nt] = t;
        }
        __builtin_amdgcn_s_setprio(0);

        // softmax: p = exp2(masked ? 0 : s); packed bf16 writes into Ps[m][j]
        #pragma unroll
        for (int nt = 0; nt < 4; nt++) {
            const unsigned int ww = (nt & 2) ? w1 : w0;
            const unsigned int wsh = ww >> ((nt & 1) * 16 + quad * 4);
            float p[4];
            p[0] = EXP2F((wsh & 1u) ? st[nt][0] : 0.0f);
            p[1] = EXP2F((wsh & 2u) ? st[nt][1] : 0.0f);
            p[2] = EXP2F((wsh & 4u) ? st[nt][2] : 0.0f);
            p[3] = EXP2F((wsh & 8u) ? st[nt][3] : 0.0f);
            const int j0 = nt * 16 + quad * 4;
            const int chunk = (j0 >> 3) ^ (mloc & 7);
            const int ci = j0 & 7;
            ushortT* dst = &Ps[mloc * 64 + chunk * 8 + ci];
            *(__hip_bfloat162*)(dst)     = __float22bfloat162_rn(make_float2(p[0], p[1]));
            *(__hip_bfloat162*)(dst + 2) = __float22bfloat162_rn(make_float2(p[2], p[3]));
        }

        // O += P @ V ; lacc += P @ ones  (Ps rows wave-private: no barrier)
        short8 pa0 = *(const short8*)&Ps[mloc * 64 + ((quad ^ (mloc & 7)) * 8)];
        short8 pa1 = *(const short8*)&Ps[mloc * 64 + (((4 + quad) ^ (mloc & 7)) * 8)];
        lacc = __builtin_amdgcn_mfma_f32_16x16x32_bf16(pa0, ones8, lacc, 0, 0, 0);
        lacc = __builtin_amdgcn_mfma_f32_16x16x32_bf16(pa1, ones8, lacc, 0, 0, 0);
        __builtin_amdgcn_s_setprio(1);
        #pragma unroll
        for (int dt = 0; dt < 4; dt++) {
            const int d = dt * 16 + l16;
            short8 vb0 = *(const short8*)&Vts[d * 64 + ((quad ^ (d & 7)) * 8)];
            short8 vb1 = *(const short8*)&Vts[d * 64 + (((4 + quad) ^ (d & 7)) * 8)];
            o[dt] = __builtin_amdgcn_mfma_f32_16x16x32_bf16(pa0, vb0, o[dt], 0, 0, 0);
            o[dt] = __builtin_amdgcn_mfma_f32_16x16x32_bf16(pa1, vb1, o[dt], 0, 0, 0);
        }
        __builtin_amdgcn_s_setprio(0);

        if (jt < 31) { w0 = wn0; w1 = wn1; }
    }

    // Normalize + store bf16.
    #pragma unroll
    for (int r = 0; r < 4; r++) {
        const float inv_l = 1.0f / lacc[r];
        const size_t row = (size_t)(b * SEQ + q0 + 16 * wave + quad * 4 + r);
        #pragma unroll
        for (int dt = 0; dt < 4; dt++) {
            attn_out[row * FEAT + h * 64 + dt * 16 + l16] = f2bf(o[dt][r] * inv_l);
        }
    }
#undef ATTN_ISSUE
#undef ATTN_WRITE
}

// ---------------------------------------------------------------------------
// Launch
// ---------------------------------------------------------------------------
extern "C" void kernel_launch(void* const* d_in, const int* in_sizes, int n_in,
                              void* d_out, int out_size, void* d_ws, size_t ws_size,
                              hipStream_t stream)
{
    const float* x      = (const float*)d_in[0];
    const int*   mask   = (const int*)d_in[1];
    const float* alpha1 = (const float*)d_in[2];
    const float* bias1  = (const float*)d_in[3];
    const float* alpha2 = (const float*)d_in[4];
    const float* bias2  = (const float*)d_in[5];
    const float* Wq     = (const float*)d_in[6];
    const float* bq     = (const float*)d_in[7];
    const float* Wk     = (const float*)d_in[8];
    const float* bk     = (const float*)d_in[9];
    const float* Wv     = (const float*)d_in[10];
    const float* bv     = (const float*)d_in[11];
    const float* Wo     = (const float*)d_in[12];
    const float* bo     = (const float*)d_in[13];
    const float* W1     = (const float*)d_in[14];
    const float* b1     = (const float*)d_in[15];
    const float* W2     = (const float*)d_in[16];
    const float* b2     = (const float*)d_in[17];
    float* out = (float*)d_out;

    char* ws = (char*)d_ws;
    const size_t MB = 1024 * 1024;
    ushortT* x2b    = (ushortT*)(ws);              // LN1 out; attn out later
    ushortT* attn_o = (ushortT*)(ws);
    ushortT* qkv    = (ushortT*)(ws + 16 * MB);    // fused q|k|v
    ushortT* x2b2   = (ushortT*)(ws + 16 * MB);    // LN2 out (after attn)
    ushortT* hbuf   = (ushortT*)(ws + 32 * MB);    // FF hidden
    ushortT* vtb    = (ushortT*)(ws + 64 * MB);
    ushortT* Wqkvt  = (ushortT*)(ws + 80 * MB);    // 6 MB  [3072][1024]
    ushortT* Wot    = (ushortT*)(ws + 86 * MB);    // 2 MB
    ushortT* W1t    = (ushortT*)(ws + 88 * MB);    // 1 MB  [512][1024]
    ushortT* W2t    = (ushortT*)(ws + 89 * MB);    // 1 MB  [1024][512]
    float*   b1p    = (float*)  (ws + 90 * MB);
    float*   bqkv   = (float*)  (ws + 90 * MB + 16384);
    unsigned int* mbits = (unsigned int*)(ws + 91 * MB); // 2 MB

    const dim3 blk(256);

    // Prep (1 launch) + mask pack
    prep_kernel<<<1281, blk, 0, stream>>>(Wq, Wk, Wv, Wo, W1, W2, bq, bk, bv, b1,
                                          Wqkvt, Wot, W1t, W2t, bqkv, b1p);
    maskbits_kernel<<<(BATCH * SEQ * SEQ) / 256, blk, 0, stream>>>(mask, mbits);

    // 1. LN1 -> bf16
    ln_kernel<<<ROWS, blk, 0, stream>>>(x, alpha1, bias1, x2b);

    // 2. Fused QKV projection
    mfma_gemm<0, 0, 1, 128><<<dim3(24, 64), blk, 0, stream>>>(
        x2b, Wqkvt, bqkv, nullptr, qkv, ROWS, QKVSTR, FEAT);

    // 3. V transpose + flash attention (512-thread blocks)
    transpose_v_kernel<<<BATCH * HEADS * (SEQ / 64), blk, 0, stream>>>(qkv + 2048, vtb);
    mfma_attn<<<BATCH * HEADS * (SEQ / AQ), dim3(512), 0, stream>>>(qkv, vtb, mbits, attn_o);

    // 4. out = x + attn @ Wo + bo
    mfma_gemm<0, 1, 0, 128><<<dim3(8, 64), blk, 0, stream>>>(
        attn_o, Wot, bo, x, out, ROWS, FEAT, FEAT);

    // 5. LN2 -> bf16
    ln_kernel<<<ROWS, blk, 0, stream>>>(out, alpha2, bias2, x2b2);

    // 6. h = ELU(x2b2 @ W1 + b1)
    mfma_gemm<1, 0, 1, 64><<<dim3(FFP / 64, 64), blk, 0, stream>>>(
        x2b2, W1t, b1p, nullptr, hbuf, ROWS, FFP, FEAT);

    // 7. out += h @ W2 + b2
    mfma_gemm<0, 1, 0, 128><<<dim3(8, 64), blk, 0, stream>>>(
        hbuf, W2t, b2, out, out, ROWS, FEAT, FFP);
}

// Round 8
// 452.930 us; speedup vs baseline: 1.3502x; 1.0144x over previous
//
#include <hip/hip_runtime.h>
#include <hip/hip_bf16.h>
#include <math.h>

// Problem constants
#define BATCH 4
#define SEQ 2048
#define FEAT 1024
#define HEADS 16
#define HDIM 64
#define FF 500
#define FFP 512                 // FF padded to multiple of 128
#define ROWS (BATCH * SEQ)      // 8192
#define QKVSTR 3072             // fused q|k|v row stride
#define AQ 256                  // attn q-rows per block (8 waves x 32 rows)

typedef unsigned short ushortT;
typedef __attribute__((ext_vector_type(8))) short short8;   // 8 bf16 (4 VGPRs)
typedef __attribute__((ext_vector_type(4))) float floatx4;  // MFMA acc

#if defined(__has_builtin) && __has_builtin(__builtin_amdgcn_exp2f)
#define EXP2F(x) __builtin_amdgcn_exp2f(x)
#else
#define EXP2F(x) exp2f(x)
#endif

__device__ __forceinline__ unsigned short f2bf(float f) {
    unsigned int u = __builtin_bit_cast(unsigned int, f);
    u += 0x7fffu + ((u >> 16) & 1u);           // RNE
    return (unsigned short)(u >> 16);
}
__device__ __forceinline__ float bf2f(short b) {
    unsigned int u = ((unsigned int)(unsigned short)b) << 16;
    return __builtin_bit_cast(float, u);
}

__device__ __forceinline__ void async16(void* lds, const void* g) {
    __builtin_amdgcn_global_load_lds(
        (const __attribute__((address_space(1))) unsigned int*)g,
        (__attribute__((address_space(3))) unsigned int*)lds, 16, 0, 0);
}

// ---------------------------------------------------------------------------
// Unified prep: 6 weight transpose+convert tiles + bias concat/pad.
// Blocks 0..1023: Wq/Wk/Wv/Wo (256 tiles each); 1024..1151: W1; 1152..1279: W2;
// 1280: biases.
// ---------------------------------------------------------------------------
__global__ void prep_kernel(const float* __restrict__ Wq, const float* __restrict__ Wk,
                            const float* __restrict__ Wv, const float* __restrict__ Wo,
                            const float* __restrict__ W1, const float* __restrict__ W2,
                            const float* __restrict__ bq, const float* __restrict__ bk,
                            const float* __restrict__ bv, const float* __restrict__ b1,
                            ushortT* __restrict__ Wqkvt, ushortT* __restrict__ Wot,
                            ushortT* __restrict__ W1t, ushortT* __restrict__ W2t,
                            float* __restrict__ bqkv, float* __restrict__ b1p)
{
    const int t = blockIdx.x;
    const int tid = threadIdx.x;
    if (t == 1280) {
        for (int i = tid; i < QKVSTR; i += 256)
            bqkv[i] = (i < 1024) ? bq[i] : ((i < 2048) ? bk[i - 1024] : bv[i - 2048]);
        for (int i = tid; i < FFP; i += 256)
            b1p[i] = (i < FF) ? b1[i] : 0.0f;
        return;
    }
    const float* W; ushortT* Wt; int K, N, Kp, bx, by;
    if (t < 1024) {
        const int wi = t >> 8, lt = t & 255;
        bx = lt & 15; by = lt >> 4; K = FEAT; N = FEAT; Kp = FEAT;
        W  = (wi == 0) ? Wq : (wi == 1) ? Wk : (wi == 2) ? Wv : Wo;
        Wt = (wi == 3) ? Wot : (Wqkvt + (size_t)wi * FEAT * FEAT);
    } else if (t < 1152) {
        const int lt = t - 1024; bx = lt & 7; by = lt >> 3;
        K = FEAT; N = FF; Kp = FEAT; W = W1; Wt = W1t;
    } else {
        const int lt = t - 1152; bx = lt & 15; by = lt >> 4;
        K = FF; N = FEAT; Kp = FFP; W = W2; Wt = W2t;
    }

    __shared__ float T[64][65];
    const int n0 = bx * 64, k0 = by * 64;
    const int r = tid >> 4;            // 0..15
    const int c = (tid & 15) * 4;      // 0..60
    #pragma unroll
    for (int i = 0; i < 4; i++) {
        const int kk = k0 + r + i * 16;
        #pragma unroll
        for (int e = 0; e < 4; e++) {
            const int nn = n0 + c + e;
            T[r + i * 16][c + e] = (kk < K && nn < N) ? W[(size_t)kk * N + nn] : 0.0f;
        }
    }
    __syncthreads();
    #pragma unroll
    for (int i = 0; i < 4; i++) {
        const int nn = r + i * 16;
        ushort4 o;
        o.x = f2bf(T[c + 0][nn]);
        o.y = f2bf(T[c + 1][nn]);
        o.z = f2bf(T[c + 2][nn]);
        o.w = f2bf(T[c + 3][nn]);
        *(ushort4*)(Wt + (size_t)(n0 + nn) * Kp + k0 + c) = o;
    }
}
// note: W1t has 512 rows allocated; rows 500..511 get zeros (T[][]=0 there),
// which is exactly the padding we want.

// ---------------------------------------------------------------------------
// Mask bit-pack: int32 0/1 [B,S,S] -> bitmask dwords [B,S,S/32].
// ---------------------------------------------------------------------------
__global__ void maskbits_kernel(const int* __restrict__ mask,
                                unsigned int* __restrict__ bits)
{
    const size_t g = (size_t)blockIdx.x * 256 + threadIdx.x;
    const int lane = threadIdx.x & 63;
    const unsigned long long bal = __ballot(mask[g] != 0);
    if (lane == 0)  bits[g >> 5] = (unsigned int)bal;
    if (lane == 32) bits[g >> 5] = (unsigned int)(bal >> 32);
}

// ---------------------------------------------------------------------------
// LayerNorm -> bf16. One block per row; wave-shuffle reduction, 1 barrier.
// ---------------------------------------------------------------------------
__global__ void ln_kernel(const float* __restrict__ x,
                          const float* __restrict__ alpha,
                          const float* __restrict__ bias,
                          ushortT* __restrict__ out)
{
    __shared__ float p1[4], p2[4];
    const int row = blockIdx.x;
    const int tid = threadIdx.x;
    const int wave = tid >> 6, lane = tid & 63;
    float4 v = ((const float4*)(x + (size_t)row * FEAT))[tid];

    float s1 = v.x + v.y + v.z + v.w;
    float s2 = v.x * v.x + v.y * v.y + v.z * v.z + v.w * v.w;
    #pragma unroll
    for (int off = 32; off > 0; off >>= 1) {
        s1 += __shfl_xor(s1, off);
        s2 += __shfl_xor(s2, off);
    }
    if (lane == 0) { p1[wave] = s1; p2[wave] = s2; }
    __syncthreads();
    const float t1 = p1[0] + p1[1] + p1[2] + p1[3];
    const float t2 = p2[0] + p2[1] + p2[2] + p2[3];
    const float mean = t1 * (1.0f / 1024.0f);
    const float var = fmaxf(t2 - 1024.0f * mean * mean, 0.0f) * (1.0f / 1023.0f);
    const float inv = 1.0f / (sqrtf(var) + 1e-6f);

    const float4 a = ((const float4*)alpha)[tid];
    const float4 b = ((const float4*)bias)[tid];
    ushort4 o;
    o.x = f2bf(a.x * (v.x - mean) * inv + b.x);
    o.y = f2bf(a.y * (v.y - mean) * inv + b.y);
    o.z = f2bf(a.z * (v.z - mean) * inv + b.z);
    o.w = f2bf(a.w * (v.w - mean) * inv + b.w);
    ((ushort4*)(out + (size_t)row * FEAT))[tid] = o;
}

// ---------------------------------------------------------------------------
// bf16 MFMA GEMM, BK=64 as two 32-K planes (keeps 64B LDS rows: conflict-free).
// 128xBN tile (BN=128: 2x2 waves, 4x4 frags; BN=64: 4x1 waves, 2x4 frags).
// XCD-chunked block swizzle (T1): each XCD gets a contiguous run of x-major
// block ids -> A row-panels reused within one XCD's L2. All grids %8 == 0.
// ---------------------------------------------------------------------------
template<int ACT, int RES, int OUT_BF16, int BN>
__global__ __launch_bounds__(256)
void mfma_gemm(const ushortT* __restrict__ A, const ushortT* __restrict__ Bt,
               const float* __restrict__ bias, const float* __restrict__ R,
               void* __restrict__ Cout, int M, int N, int K)
{
    constexpr int MT = (BN == 128) ? 4 : 2;
    constexpr int MSPAN = (BN == 128) ? 64 : 32;
    __shared__ ushortT As[2][128 * 32];
    __shared__ ushortT Bs[2][BN * 32];

    const int tid  = threadIdx.x;
    const int wave = tid >> 6, lane = tid & 63;
    const int quad = lane >> 4, l16 = lane & 15;
    const int wm = (BN == 128) ? (wave >> 1) : wave;
    const int wn = (BN == 128) ? (wave & 1) : 0;

    const int nbx = gridDim.x;
    int lid = blockIdx.y * nbx + blockIdx.x;
    const int cpx = (nbx * gridDim.y) >> 3;     // grid %8 == 0 for all launches
    lid = (lid & 7) * cpx + (lid >> 3);
    const int row0 = (lid / nbx) * 128, col0 = (lid % nbx) * BN;

    const floatx4 z4 = {0.f, 0.f, 0.f, 0.f};
    floatx4 acc[MT][4];
    #pragma unroll
    for (int i = 0; i < MT; i++)
        #pragma unroll
        for (int j = 0; j < 4; j++) acc[i][j] = z4;

    for (int k0 = 0; k0 < K; k0 += 64) {
        __syncthreads();
        #pragma unroll
        for (int kh = 0; kh < 2; kh++) {
            #pragma unroll
            for (int i = 0; i < 2; i++) {
                const int rbase = 16 * (wave + 4 * i);
                const int r = rbase + (lane >> 2);
                const int co = (lane & 3) * 8;
                async16((char*)As[kh] + rbase * 64,
                        A + (size_t)(row0 + r) * K + k0 + kh * 32 + co);
            }
            if (BN == 128) {
                #pragma unroll
                for (int i = 0; i < 2; i++) {
                    const int rbase = 16 * (wave + 4 * i);
                    const int r = rbase + (lane >> 2);
                    const int co = (lane & 3) * 8;
                    async16((char*)Bs[kh] + rbase * 64,
                            Bt + (size_t)(col0 + r) * K + k0 + kh * 32 + co);
                }
            } else {
                const int rbase = 16 * wave;
                const int r = rbase + (lane >> 2);
                const int co = (lane & 3) * 8;
                async16((char*)Bs[kh] + rbase * 64,
                        Bt + (size_t)(col0 + r) * K + k0 + kh * 32 + co);
            }
        }
        __syncthreads();

        #pragma unroll
        for (int kh = 0; kh < 2; kh++) {
            short8 af[MT], bf[4];
            #pragma unroll
            for (int mt = 0; mt < MT; mt++)
                af[mt] = *(const short8*)&As[kh][(MSPAN * wm + 16 * mt + l16) * 32 + quad * 8];
            #pragma unroll
            for (int nt = 0; nt < 4; nt++)
                bf[nt] = *(const short8*)&Bs[kh][(64 * wn + 16 * nt + l16) * 32 + quad * 8];
            #pragma unroll
            for (int mt = 0; mt < MT; mt++)
                #pragma unroll
                for (int nt = 0; nt < 4; nt++)
                    acc[mt][nt] = __builtin_amdgcn_mfma_f32_16x16x32_bf16(
                        af[mt], bf[nt], acc[mt][nt], 0, 0, 0);
        }
    }

    #pragma unroll
    for (int mt = 0; mt < MT; mt++) {
        #pragma unroll
        for (int nt = 0; nt < 4; nt++) {
            const int col = col0 + 64 * wn + 16 * nt + l16;
            #pragma unroll
            for (int r = 0; r < 4; r++) {
                const int row = row0 + MSPAN * wm + 16 * mt + quad * 4 + r;
                float val = acc[mt][nt][r] + bias[col];
                if (ACT == 1) val = (val > 0.0f) ? val : (__expf(val) - 1.0f);
                if (RES) val += R[(size_t)row * N + col];
                if (OUT_BF16)
                    ((ushortT*)Cout)[(size_t)row * N + col] = f2bf(val);
                else
                    ((float*)Cout)[(size_t)row * N + col] = val;
            }
        }
    }
}

// ---------------------------------------------------------------------------
// V transpose: v bf16 (rows stride QKVSTR) -> vt bf16 [B][H][64 d][SEQ j]
// ---------------------------------------------------------------------------
__global__ void transpose_v_kernel(const ushortT* __restrict__ v, ushortT* __restrict__ vt)
{
    __shared__ ushortT T[64][80];
    const int bid = blockIdx.x;
    const int jt = bid & 31, h = (bid >> 5) & 15, b = bid >> 9;
    const int j0 = jt * 64;
    const int tid = threadIdx.x;

    const int j = tid >> 2;
    #pragma unroll
    for (int i = 0; i < 2; i++) {
        const int c = (tid & 3) * 2 + i;
        short8 val = *(const short8*)(v + (size_t)(b * SEQ + j0 + j) * QKVSTR + h * 64 + c * 8);
        *(short8*)&T[j][c * 8] = val;
    }
    __syncthreads();
    const int d = tid >> 2;
    #pragma unroll
    for (int i = 0; i < 2; i++) {
        const int cj = (tid & 3) * 2 + i;
        union { short8 v8; ushortT u[8]; } tmp;
        #pragma unroll
        for (int e = 0; e < 8; e++) tmp.u[e] = T[cj * 8 + e][d];
        *(short8*)(vt + ((size_t)((b * HEADS + h) * 64 + d)) * SEQ + j0 + cj * 8) = tmp.v8;
    }
}

// ---------------------------------------------------------------------------
// MFMA flash attention, 8 waves x 32 q-rows (AQ=256). Round-7 lesson: 39%
// occupancy cap was NOT LDS-residency; single-buffer's extra barrier cost 8us.
// Round-8 attacks the LDS-bandwidth floor instead: per-wave K/V fragment
// reads serve 32 rows (2 m-groups share each K/V frag read, round-5 body) and
// staging serves 256 rows -> LDS bytes per 128 q-rows drop 176KB -> 104KB.
// dbuf K/V (1 barrier/tile, proven), Ps-LDS P path, XCD swizzle, setprio,
// mask prefetch. LDS = 64KB -> exactly 2 blocks/CU, grid 512 = 2/CU: full
// residency, zero tail.
// ---------------------------------------------------------------------------
__global__ __launch_bounds__(512)
void mfma_attn(const ushortT* __restrict__ qkv, const ushortT* __restrict__ vt,
               const unsigned int* __restrict__ mbits, ushortT* __restrict__ attn_out)
{
    __shared__ ushortT Ks[2][64 * 64];    // [j][d] swizzled
    __shared__ ushortT Vts[2][64 * 64];   // [d][j] swizzled
    __shared__ ushortT Ps[AQ * 64];       // [m][j] swizzled, wave-private rows

    const int tid = threadIdx.x;
    const int wave = tid >> 6, lane = tid & 63;   // wave 0..7
    const int quad = lane >> 4, l16 = lane & 15;
    // XCD-aware bijective swizzle (grid=512, 512%8==0): raw%8 = XCD.
    const int bid = ((blockIdx.x & 7) << 6) | (blockIdx.x >> 3);
    const int qt = bid & 7, h = (bid >> 3) & 15, b = bid >> 7;
    const int q0 = qt * AQ;

    const ushortT* qptr = qkv;
    const ushortT* kptr = qkv + 1024;

    // Q fragments for both m-groups (rows q0 + 32*wave + mg*16 + ...).
    short8 qf[2][2];
    #pragma unroll
    for (int mg = 0; mg < 2; mg++) {
        const size_t qrow = (size_t)(b * SEQ + q0 + 32 * wave + mg * 16 + l16);
        short8 t0 = *(const short8*)(qptr + qrow * QKVSTR + h * 64 + quad * 8);
        short8 t1 = *(const short8*)(qptr + qrow * QKVSTR + h * 64 + 32 + quad * 8);
        const float cs = 0.125f * 1.4426950408889634f;
        #pragma unroll
        for (int i = 0; i < 8; i++) {
            qf[mg][0][i] = (short)f2bf(bf2f(t0[i]) * cs);
            qf[mg][1][i] = (short)f2bf(bf2f(t1[i]) * cs);
        }
    }

    short8 ones8;
    #pragma unroll
    for (int i = 0; i < 8; i++) ones8[i] = (short)0x3F80;  // bf16 1.0

    const floatx4 z4 = {0.f, 0.f, 0.f, 0.f};
    floatx4 o[2][4];
    #pragma unroll
    for (int mg = 0; mg < 2; mg++)
        #pragma unroll
        for (int dt = 0; dt < 4; dt++) o[mg][dt] = z4;
    floatx4 lacc[2] = {z4, z4};

    // staging: 512 threads, one K short8 + one V short8 each (16KB K + 16KB V).
    const int rr = tid >> 3;            // 0..63
    const int c0 = tid & 7;             // 0..7
    const ushortT* gk = kptr + (size_t)(b * SEQ + rr) * QKVSTR + h * 64 + c0 * 8;
    const ushortT* gv = vt + ((size_t)((b * HEADS + h) * 64 + rr)) * SEQ + c0 * 8;
    short8 rk, rv;

#define ATTN_ISSUE() {                                                       \
    rk = *(const short8*)gk;                                                 \
    rv = *(const short8*)gv;                                                 \
    gk += (size_t)64 * QKVSTR; gv += 64; }

#define ATTN_WRITE(BI) {                                                     \
    *(short8*)&Ks[BI][rr * 64 + ((c0 ^ (rr & 7)) * 8)] = rk;                 \
    *(short8*)&Vts[BI][rr * 64 + ((c0 ^ (rr & 7)) * 8)] = rv; }

    const unsigned int* mrowp[2];
    mrowp[0] = mbits + (size_t)(b * SEQ + q0 + 32 * wave + l16) * (SEQ / 32);
    mrowp[1] = mrowp[0] + 16 * (SEQ / 32);
    const int mloc0 = 32 * wave + l16;

    // Prologue: stage tile 0; preload mask words for tile 0.
    ATTN_ISSUE();
    ATTN_WRITE(0);
    unsigned int w[2][2];
    #pragma unroll
    for (int mg = 0; mg < 2; mg++) {
        w[mg][0] = mrowp[mg][0];
        w[mg][1] = mrowp[mg][1];
    }

    #pragma unroll 2
    for (int jt = 0; jt < 32; jt++) {
        __syncthreads();
        const int cur = jt & 1;
        unsigned int wn[2][2];
        if (jt < 31) {
            ATTN_ISSUE();
            #pragma unroll
            for (int mg = 0; mg < 2; mg++) {
                wn[mg][0] = mrowp[mg][jt * 2 + 2];
                wn[mg][1] = mrowp[mg][jt * 2 + 3];
            }
        }

        // S^T = K @ Q^T for both m-groups (K frags read once)
        floatx4 st[2][4];
        __builtin_amdgcn_s_setprio(1);
        #pragma unroll
        for (int nt = 0; nt < 4; nt++) {
            const int j = nt * 16 + l16;
            short8 ka0 = *(const short8*)&Ks[cur][j * 64 + ((quad ^ (j & 7)) * 8)];
            short8 ka1 = *(const short8*)&Ks[cur][j * 64 + (((4 + quad) ^ (j & 7)) * 8)];
            #pragma unroll
            for (int mg = 0; mg < 2; mg++) {
                floatx4 t = z4;
                t = __builtin_amdgcn_mfma_f32_16x16x32_bf16(ka0, qf[mg][0], t, 0, 0, 0);
                t = __builtin_amdgcn_mfma_f32_16x16x32_bf16(ka1, qf[mg][1], t, 0, 0, 0);
                st[mg][nt] = t;
            }
        }
        __builtin_amdgcn_s_setprio(0);

        // softmax: p = exp2(masked ? 0 : s); packed bf16 writes into Ps[m][j]
        #pragma unroll
        for (int mg = 0; mg < 2; mg++) {
            const int mloc = mloc0 + mg * 16;
            #pragma unroll
            for (int nt = 0; nt < 4; nt++) {
                const unsigned int ww = (nt & 2) ? w[mg][1] : w[mg][0];
                const unsigned int wsh = ww >> ((nt & 1) * 16 + quad * 4);
                float p[4];
                p[0] = EXP2F((wsh & 1u) ? st[mg][nt][0] : 0.0f);
                p[1] = EXP2F((wsh & 2u) ? st[mg][nt][1] : 0.0f);
                p[2] = EXP2F((wsh & 4u) ? st[mg][nt][2] : 0.0f);
                p[3] = EXP2F((wsh & 8u) ? st[mg][nt][3] : 0.0f);
                const int j0 = nt * 16 + quad * 4;
                const int chunk = (j0 >> 3) ^ (mloc & 7);
                const int ci = j0 & 7;
                ushortT* dst = &Ps[mloc * 64 + chunk * 8 + ci];
                *(__hip_bfloat162*)(dst)     = __float22bfloat162_rn(make_float2(p[0], p[1]));
                *(__hip_bfloat162*)(dst + 2) = __float22bfloat162_rn(make_float2(p[2], p[3]));
            }
        }

        // O += P @ V ; lacc += P @ ones  (Ps rows wave-private: no barrier)
        short8 pa[2][2];
        #pragma unroll
        for (int mg = 0; mg < 2; mg++) {
            const int mloc = mloc0 + mg * 16;
            pa[mg][0] = *(const short8*)&Ps[mloc * 64 + ((quad ^ (mloc & 7)) * 8)];
            pa[mg][1] = *(const short8*)&Ps[mloc * 64 + (((4 + quad) ^ (mloc & 7)) * 8)];
            lacc[mg] = __builtin_amdgcn_mfma_f32_16x16x32_bf16(pa[mg][0], ones8, lacc[mg], 0, 0, 0);
            lacc[mg] = __builtin_amdgcn_mfma_f32_16x16x32_bf16(pa[mg][1], ones8, lacc[mg], 0, 0, 0);
        }
        __builtin_amdgcn_s_setprio(1);
        #pragma unroll
        for (int dt = 0; dt < 4; dt++) {
            const int d = dt * 16 + l16;
            short8 vb0 = *(const short8*)&Vts[cur][d * 64 + ((quad ^ (d & 7)) * 8)];
            short8 vb1 = *(const short8*)&Vts[cur][d * 64 + (((4 + quad) ^ (d & 7)) * 8)];
            #pragma unroll
            for (int mg = 0; mg < 2; mg++) {
                o[mg][dt] = __builtin_amdgcn_mfma_f32_16x16x32_bf16(pa[mg][0], vb0, o[mg][dt], 0, 0, 0);
                o[mg][dt] = __builtin_amdgcn_mfma_f32_16x16x32_bf16(pa[mg][1], vb1, o[mg][dt], 0, 0, 0);
            }
        }
        __builtin_amdgcn_s_setprio(0);

        if (jt < 31) {
            ATTN_WRITE(cur ^ 1);
            #pragma unroll
            for (int mg = 0; mg < 2; mg++) {
                w[mg][0] = wn[mg][0];
                w[mg][1] = wn[mg][1];
            }
        }
    }

    // Normalize + store bf16.
    #pragma unroll
    for (int mg = 0; mg < 2; mg++) {
        #pragma unroll
        for (int r = 0; r < 4; r++) {
            const float inv_l = 1.0f / lacc[mg][r];
            const size_t row = (size_t)(b * SEQ + q0 + 32 * wave + mg * 16 + quad * 4 + r);
            #pragma unroll
            for (int dt = 0; dt < 4; dt++) {
                attn_out[row * FEAT + h * 64 + dt * 16 + l16] = f2bf(o[mg][dt][r] * inv_l);
            }
        }
    }
#undef ATTN_ISSUE
#undef ATTN_WRITE
}

// ---------------------------------------------------------------------------
// Launch
// ---------------------------------------------------------------------------
extern "C" void kernel_launch(void* const* d_in, const int* in_sizes, int n_in,
                              void* d_out, int out_size, void* d_ws, size_t ws_size,
                              hipStream_t stream)
{
    const float* x      = (const float*)d_in[0];
    const int*   mask   = (const int*)d_in[1];
    const float* alpha1 = (const float*)d_in[2];
    const float* bias1  = (const float*)d_in[3];
    const float* alpha2 = (const float*)d_in[4];
    const float* bias2  = (const float*)d_in[5];
    const float* Wq     = (const float*)d_in[6];
    const float* bq     = (const float*)d_in[7];
    const float* Wk     = (const float*)d_in[8];
    const float* bk     = (const float*)d_in[9];
    const float* Wv     = (const float*)d_in[10];
    const float* bv     = (const float*)d_in[11];
    const float* Wo     = (const float*)d_in[12];
    const float* bo     = (const float*)d_in[13];
    const float* W1     = (const float*)d_in[14];
    const float* b1     = (const float*)d_in[15];
    const float* W2     = (const float*)d_in[16];
    const float* b2     = (const float*)d_in[17];
    float* out = (float*)d_out;

    char* ws = (char*)d_ws;
    const size_t MB = 1024 * 1024;
    ushortT* x2b    = (ushortT*)(ws);              // LN1 out; attn out later
    ushortT* attn_o = (ushortT*)(ws);
    ushortT* qkv    = (ushortT*)(ws + 16 * MB);    // fused q|k|v
    ushortT* x2b2   = (ushortT*)(ws + 16 * MB);    // LN2 out (after attn)
    ushortT* hbuf   = (ushortT*)(ws + 32 * MB);    // FF hidden
    ushortT* vtb    = (ushortT*)(ws + 64 * MB);
    ushortT* Wqkvt  = (ushortT*)(ws + 80 * MB);    // 6 MB  [3072][1024]
    ushortT* Wot    = (ushortT*)(ws + 86 * MB);    // 2 MB
    ushortT* W1t    = (ushortT*)(ws + 88 * MB);    // 1 MB  [512][1024]
    ushortT* W2t    = (ushortT*)(ws + 89 * MB);    // 1 MB  [1024][512]
    float*   b1p    = (float*)  (ws + 90 * MB);
    float*   bqkv   = (float*)  (ws + 90 * MB + 16384);
    unsigned int* mbits = (unsigned int*)(ws + 91 * MB); // 2 MB

    const dim3 blk(256);

    // Prep (1 launch) + mask pack
    prep_kernel<<<1281, blk, 0, stream>>>(Wq, Wk, Wv, Wo, W1, W2, bq, bk, bv, b1,
                                          Wqkvt, Wot, W1t, W2t, bqkv, b1p);
    maskbits_kernel<<<(BATCH * SEQ * SEQ) / 256, blk, 0, stream>>>(mask, mbits);

    // 1. LN1 -> bf16
    ln_kernel<<<ROWS, blk, 0, stream>>>(x, alpha1, bias1, x2b);

    // 2. Fused QKV projection
    mfma_gemm<0, 0, 1, 128><<<dim3(24, 64), blk, 0, stream>>>(
        x2b, Wqkvt, bqkv, nullptr, qkv, ROWS, QKVSTR, FEAT);

    // 3. V transpose + flash attention (512-thread blocks, AQ=256)
    transpose_v_kernel<<<BATCH * HEADS * (SEQ / 64), blk, 0, stream>>>(qkv + 2048, vtb);
    mfma_attn<<<BATCH * HEADS * (SEQ / AQ), dim3(512), 0, stream>>>(qkv, vtb, mbits, attn_o);

    // 4. out = x + attn @ Wo + bo
    mfma_gemm<0, 1, 0, 128><<<dim3(8, 64), blk, 0, stream>>>(
        attn_o, Wot, bo, x, out, ROWS, FEAT, FEAT);

    // 5. LN2 -> bf16
    ln_kernel<<<ROWS, blk, 0, stream>>>(out, alpha2, bias2, x2b2);

    // 6. h = ELU(x2b2 @ W1 + b1)
    mfma_gemm<1, 0, 1, 64><<<dim3(FFP / 64, 64), blk, 0, stream>>>(
        x2b2, W1t, b1p, nullptr, hbuf, ROWS, FFP, FEAT);

    // 7. out += h @ W2 + b2
    mfma_gemm<0, 1, 0, 128><<<dim3(8, 64), blk, 0, stream>>>(
        hbuf, W2t, b2, out, out, ROWS, FEAT, FFP);
}